// Round 1
// baseline (13269.746 us; speedup 1.0000x reference)
//
#include <hip/hip_runtime.h>
#include <cstdint>
#include <cstddef>

constexpr int NB  = 2;     // batch
constexpr int CO  = 64;    // out channels (both layers)
constexpr int DIM = 64;    // spatial
constexpr int SP  = DIM * DIM * DIM;       // 262144
constexpr int NC  = NB * CO;               // 128 (n,c) pairs
constexpr int Y_SZ = NB * CO * 32 * 32 * 32;  // 4,194,304

// ---------------------------------------------------------------- gate ----
// g[n][e][co] = softmax_e( t[n] . gw[e*64+co] + gb[e*64+co] )
__global__ void gate_kernel(const float* __restrict__ t, const float* __restrict__ gw,
                            const float* __restrict__ gb, float* __restrict__ g) {
    int tid = threadIdx.x;            // 0..127
    if (tid >= NB * CO) return;
    int n = tid >> 6, co = tid & 63;
    float tl[10];
#pragma unroll
    for (int k = 0; k < 10; ++k) tl[k] = t[n * 10 + k];
    float l[5];
#pragma unroll
    for (int e = 0; e < 5; ++e) {
        int row = e * CO + co;
        float acc = gb[row];
#pragma unroll
        for (int k = 0; k < 10; ++k) acc += tl[k] * gw[row * 10 + k];
        l[e] = acc;
    }
    float m = l[0];
#pragma unroll
    for (int e = 1; e < 5; ++e) m = fmaxf(m, l[e]);
    float s = 0.f;
#pragma unroll
    for (int e = 0; e < 5; ++e) { l[e] = expf(l[e] - m); s += l[e]; }
    float inv = 1.f / s;
#pragma unroll
    for (int e = 0; e < 5; ++e) g[(n * 5 + e) * CO + co] = l[e] * inv;
}

// --------------------------------------------------------------- synth ----
// wbuf layout: [n][ci][tap(125)][co]  (co contiguous for float4 conv reads)
template <int CI>
__global__ void synth_kernel(const float* __restrict__ g,
                             const float* __restrict__ c5, const float* __restrict__ c3,
                             const float* __restrict__ c1, const float* __restrict__ a3,
                             const float* __restrict__ a5, float* __restrict__ wbuf) {
    int idx = blockIdx.x * 256 + threadIdx.x;
    constexpr int TOTAL = NB * CO * CI * 125;
    if (idx >= TOTAL) return;
    int tap = idx % 125;
    int ci  = (idx / 125) % CI;
    int co  = (idx / (125 * CI)) % CO;
    int n   = idx / (125 * CI * CO);
    const float* gn = g + n * 5 * CO;
    float g0 = gn[0 * CO + co], g1 = gn[1 * CO + co], g2 = gn[2 * CO + co],
          g3 = gn[3 * CO + co], g4 = gn[4 * CO + co];
    int dz = tap / 25, dy = (tap / 5) % 5, dx = tap % 5;
    int oc = co * CI + ci;
    float v = g0 * c5[(size_t)oc * 125 + tap] + g4 * a5[oc] * (1.f / 125.f);
    if (dz >= 1 && dz <= 3 && dy >= 1 && dy <= 3 && dx >= 1 && dx <= 3)
        v += g1 * c3[(size_t)oc * 27 + (dz - 1) * 9 + (dy - 1) * 3 + (dx - 1)]
           + g3 * a3[oc] * (1.f / 27.f);
    if (dz == 2 && dy == 2 && dx == 2) v += g2 * c1[oc];
    wbuf[((size_t)(n * CI + ci) * 125 + tap) * CO + co] = v;
}

// ---------------------------------------------------------------- conv ----
// Direct 5x5x5 SAME conv. Block tile: 16 co x 4 y x 64 x (fixed n, z).
// Thread: 4 co x 4 x accumulators. Input tile in LDS (row padded to 69).
template <int CI>
__global__ __launch_bounds__(256, 2) void conv5_kernel(const float* __restrict__ x,
                                                       const float* __restrict__ wbuf,
                                                       float* __restrict__ out) {
    constexpr int CICH = 4;
    __shared__ float xs[CICH][5][8][69];
    int b    = blockIdx.x;
    int co_t = b & 3;
    int y_t  = (b >> 2) & 15;
    int z    = (b >> 6) & 63;
    int n    = b >> 12;
    int tid  = threadIdx.x;
    int x_grp = tid & 15;
    int y_i   = (tid >> 4) & 3;
    int co_g  = tid >> 6;          // wave index == co group -> wave-uniform weights
    int x0    = x_grp * 4;

    float acc[4][4];
#pragma unroll
    for (int j = 0; j < 4; ++j)
#pragma unroll
        for (int i = 0; i < 4; ++i) acc[j][i] = 0.f;

    const float* xn = x + (size_t)n * CI * SP;

    for (int cb = 0; cb < CI / CICH; ++cb) {
        // -------- stage input tile (with halo, zero-padded) --------
        for (int idx = tid; idx < CICH * 5 * 8 * 69; idx += 256) {
            int xx = idx % 69;
            int r  = idx / 69;
            int yy = r & 7;  r >>= 3;
            int dz = r % 5;
            int c  = r / 5;
            int zi = z + dz - 2;
            int yi = y_t * 4 + yy - 2;
            int xi = xx - 2;
            float v = 0.f;
            if ((unsigned)zi < 64u && (unsigned)yi < 64u && (unsigned)xi < 64u)
                v = xn[((size_t)(cb * CICH + c) * 64 + zi) * 4096 + yi * 64 + xi];
            xs[c][dz][yy][xx] = v;
        }
        __syncthreads();

        const float* wp = wbuf + (size_t)(n * CI + cb * CICH) * 125 * CO
                        + co_t * 16 + co_g * 4;
#pragma unroll 1
        for (int c = 0; c < CICH; ++c) {
#pragma unroll 1
            for (int dz = 0; dz < 5; ++dz) {
#pragma unroll
                for (int dy = 0; dy < 5; ++dy) {
                    float xr[8];
#pragma unroll
                    for (int k = 0; k < 8; ++k) xr[k] = xs[c][dz][y_i + dy][x0 + k];
#pragma unroll
                    for (int dx = 0; dx < 5; ++dx) {
                        float4 w4 = *reinterpret_cast<const float4*>(
                            wp + ((size_t)c * 125 + dz * 25 + dy * 5 + dx) * CO);
#pragma unroll
                        for (int i = 0; i < 4; ++i) {
                            acc[0][i] += w4.x * xr[i + dx];
                            acc[1][i] += w4.y * xr[i + dx];
                            acc[2][i] += w4.z * xr[i + dx];
                            acc[3][i] += w4.w * xr[i + dx];
                        }
                    }
                }
            }
        }
        __syncthreads();
    }

    int y = y_t * 4 + y_i;
#pragma unroll
    for (int j = 0; j < 4; ++j) {
        int co = co_t * 16 + co_g * 4 + j;
        float4 v = make_float4(acc[j][0], acc[j][1], acc[j][2], acc[j][3]);
        *reinterpret_cast<float4*>(out + ((size_t)(n * CO + co) * 64 + z) * 4096
                                   + y * 64 + x0) = v;
    }
}

// --------------------------------------------------------------- stats ----
// One block per (n,c): mean and inv_std over S spatial elements.
__global__ void stats_kernel(const float* __restrict__ in, float* __restrict__ stats, int S) {
    int nc = blockIdx.x;
    const float4* p = reinterpret_cast<const float4*>(in + (size_t)nc * S);
    float s = 0.f, s2 = 0.f;
    int S4 = S >> 2;
    for (int i = threadIdx.x; i < S4; i += 256) {
        float4 v = p[i];
        s  += v.x + v.y + v.z + v.w;
        s2 += v.x * v.x + v.y * v.y + v.z * v.z + v.w * v.w;
    }
    __shared__ float sh[256], sh2[256];
    sh[threadIdx.x] = s; sh2[threadIdx.x] = s2;
    __syncthreads();
    for (int o = 128; o > 0; o >>= 1) {
        if (threadIdx.x < o) {
            sh[threadIdx.x]  += sh[threadIdx.x + o];
            sh2[threadIdx.x] += sh2[threadIdx.x + o];
        }
        __syncthreads();
    }
    if (threadIdx.x == 0) {
        float mean = sh[0] / S;
        float var  = sh2[0] / S - mean * mean;
        stats[nc * 2]     = mean;
        stats[nc * 2 + 1] = rsqrtf(var + 1e-5f);
    }
}

// ----------------------------------------------------------- norm+mish ----
// In-place: buf = mish( (buf - mean) * inv_std * gamma + beta ), float4.
template <int SHIFT>   // log2(S), S = spatial size per (n,c)
__global__ void norm_mish_kernel(float* __restrict__ buf, const float* __restrict__ stats,
                                 const float* __restrict__ gamma, const float* __restrict__ beta,
                                 int total4) {
    int idx = blockIdx.x * 256 + threadIdx.x;
    if (idx >= total4) return;
    float4 v = reinterpret_cast<float4*>(buf)[idx];
    int nc = idx >> (SHIFT - 2);
    int c  = nc & 63;
    float mean = stats[nc * 2], inv = stats[nc * 2 + 1];
    float ga = gamma[c], be = beta[c];
    float* pv = &v.x;
#pragma unroll
    for (int k = 0; k < 4; ++k) {
        float xh = (pv[k] - mean) * inv * ga + be;
        float sp = (xh > 20.f) ? xh : log1pf(expf(xh));       // softplus
        float th = 1.f - 2.f / (expf(2.f * sp) + 1.f);        // tanh(sp), sp>=0
        pv[k] = xh * th;
    }
    reinterpret_cast<float4*>(buf)[idx] = v;
}

// ----------------------------------------------------------- down conv ----
// 2x2x2 stride-2 VALID conv, Ci=Co=64; out (n,co,32,32,32) raw (pre-norm).
__global__ __launch_bounds__(256) void down_conv_kernel(const float* __restrict__ xin,
                                                        const float* __restrict__ dw,
                                                        float* __restrict__ out) {
    __shared__ float ls[8][2][8][64];
    int b   = blockIdx.x;
    int yt  = b & 7;
    int z   = (b >> 3) & 31;
    int n   = b >> 8;
    int tid = threadIdx.x;
    int xo  = tid & 31;
    int cog = tid >> 5;  // 0..7 -> 8 co each

    float acc[4][8];
#pragma unroll
    for (int yo = 0; yo < 4; ++yo)
#pragma unroll
        for (int j = 0; j < 8; ++j) acc[yo][j] = 0.f;

    for (int cc = 0; cc < 8; ++cc) {
        for (int idx = tid; idx < 8192; idx += 256) {
            int xx = idx & 63;
            int yy = (idx >> 6) & 7;
            int dz = (idx >> 9) & 1;
            int c  = idx >> 10;
            ls[c][dz][yy][xx] = xin[((size_t)(n * CO + cc * 8 + c) * 64 + 2 * z + dz) * 4096
                                    + (yt * 8 + yy) * 64 + xx];
        }
        __syncthreads();
#pragma unroll 1
        for (int c = 0; c < 8; ++c) {
            int ci = cc * 8 + c;
#pragma unroll
            for (int tap = 0; tap < 8; ++tap) {
                int dz = tap >> 2, dy = (tap >> 1) & 1, dx = tap & 1;
                float w[8];
#pragma unroll
                for (int j = 0; j < 8; ++j)
                    w[j] = dw[((size_t)(cog * 8 + j) * CO + ci) * 8 + tap];
#pragma unroll
                for (int yo = 0; yo < 4; ++yo) {
                    float xv = ls[c][dz][yo * 2 + dy][2 * xo + dx];
#pragma unroll
                    for (int j = 0; j < 8; ++j) acc[yo][j] += w[j] * xv;
                }
            }
        }
        __syncthreads();
    }
#pragma unroll
    for (int yo = 0; yo < 4; ++yo)
#pragma unroll
        for (int j = 0; j < 8; ++j)
            out[((size_t)(n * CO + cog * 8 + j) * 32 + z) * 1024 + (yt * 4 + yo) * 32 + xo]
                = acc[yo][j];
}

// -------------------------------------------------------------- launch ----
extern "C" void kernel_launch(void* const* d_in, const int* in_sizes, int n_in,
                              void* d_out, int out_size, void* d_ws, size_t ws_size,
                              hipStream_t stream) {
    const float* x      = (const float*)d_in[0];
    const float* t      = (const float*)d_in[1];
    const float* l1_c5  = (const float*)d_in[2];
    const float* l1_c3  = (const float*)d_in[3];
    const float* l1_c1  = (const float*)d_in[4];
    const float* l1_a3  = (const float*)d_in[5];
    const float* l1_a5  = (const float*)d_in[6];
    const float* l1_gw  = (const float*)d_in[7];
    const float* l1_gb  = (const float*)d_in[8];
    const float* l1_ga  = (const float*)d_in[9];
    const float* l1_be  = (const float*)d_in[10];
    const float* l2_c5  = (const float*)d_in[11];
    const float* l2_c3  = (const float*)d_in[12];
    const float* l2_c1  = (const float*)d_in[13];
    const float* l2_a3  = (const float*)d_in[14];
    const float* l2_a5  = (const float*)d_in[15];
    const float* l2_gw  = (const float*)d_in[16];
    const float* l2_gb  = (const float*)d_in[17];
    const float* l2_ga  = (const float*)d_in[18];
    const float* l2_be  = (const float*)d_in[19];
    const float* down_w = (const float*)d_in[20];
    const float* dn_ga  = (const float*)d_in[21];
    const float* dn_be  = (const float*)d_in[22];

    char* ws = (char*)d_ws;
    // workspace layout (bytes)
    float* h  = (float*)(ws);                                   // 134,217,728 B
    float* w1 = (float*)(ws + 134217728);                       //   2,048,000 B
    float* w2 = (float*)(ws + 134217728 + 2048000);             //   4,096,000 B
    float* g1 = (float*)(ws + 134217728 + 2048000 + 4096000);   //       2,560 B
    float* g2 = (float*)(ws + 134217728 + 2048000 + 4096000 + 2560);
    float* st = (float*)(ws + 134217728 + 2048000 + 4096000 + 5120);

    float* yout  = (float*)d_out;          // (2,64,32,32,32)
    float* xskip = (float*)d_out + Y_SZ;   // (2,64,64,64,64)

    // gates
    gate_kernel<<<1, 128, 0, stream>>>(t, l1_gw, l1_gb, g1);
    gate_kernel<<<1, 128, 0, stream>>>(t, l2_gw, l2_gb, g2);
    // synthesized per-sample kernels
    synth_kernel<32><<<(NB * CO * 32 * 125 + 255) / 256, 256, 0, stream>>>(
        g1, l1_c5, l1_c3, l1_c1, l1_a3, l1_a5, w1);
    synth_kernel<64><<<(NB * CO * 64 * 125 + 255) / 256, 256, 0, stream>>>(
        g2, l2_c5, l2_c3, l2_c1, l2_a3, l2_a5, w2);

    // layer 1: conv -> stats -> norm+mish (in place in ws)
    conv5_kernel<32><<<NB * 64 * 16 * 4, 256, 0, stream>>>(x, w1, h);
    stats_kernel<<<NC, 256, 0, stream>>>(h, st, SP);
    norm_mish_kernel<18><<<(NC * SP / 4 + 255) / 256, 256, 0, stream>>>(
        h, st, l1_ga, l1_be, NC * SP / 4);

    // layer 2: conv (raw into x_skip region) -> stats -> norm+mish in place
    conv5_kernel<64><<<NB * 64 * 16 * 4, 256, 0, stream>>>(h, w2, xskip);
    stats_kernel<<<NC, 256, 0, stream>>>(xskip, st, SP);
    norm_mish_kernel<18><<<(NC * SP / 4 + 255) / 256, 256, 0, stream>>>(
        xskip, st, l2_ga, l2_be, NC * SP / 4);

    // downsample: conv raw into y region -> stats -> norm+mish in place
    down_conv_kernel<<<NB * 32 * 8, 256, 0, stream>>>(xskip, down_w, yout);
    stats_kernel<<<NC, 256, 0, stream>>>(yout, st, 32768);
    norm_mish_kernel<15><<<(NC * 32768 / 4 + 255) / 256, 256, 0, stream>>>(
        yout, st, dn_ga, dn_be, NC * 32768 / 4);
}

// Round 2
// 1918.526 us; speedup vs baseline: 6.9166x; 6.9166x over previous
//
#include <hip/hip_runtime.h>
#include <cstdint>
#include <cstddef>

constexpr int NB  = 2;     // batch
constexpr int CO  = 64;    // out channels (both layers)
constexpr int DIM = 64;    // spatial
constexpr int SP  = DIM * DIM * DIM;       // 262144
constexpr int NC  = NB * CO;               // 128 (n,c) pairs
constexpr int Y_SZ = NB * CO * 32 * 32 * 32;  // 4,194,304

typedef float f32x4 __attribute__((ext_vector_type(4)));
typedef short s16x8 __attribute__((ext_vector_type(8)));

__device__ __forceinline__ unsigned short f2bf(float f) {
    unsigned int u = __float_as_uint(f);
    unsigned int r = (u + 0x7fffu + ((u >> 16) & 1u)) >> 16;
    return (unsigned short)r;
}
__device__ __forceinline__ float bf2f(unsigned short u) {
    return __uint_as_float((unsigned int)u << 16);
}
__device__ __forceinline__ unsigned int pack2(float a, float b) {
    return (unsigned int)f2bf(a) | ((unsigned int)f2bf(b) << 16);
}

// ---------------------------------------------------------------- gate ----
__global__ void gate_kernel(const float* __restrict__ t, const float* __restrict__ gw,
                            const float* __restrict__ gb, float* __restrict__ g) {
    int tid = threadIdx.x;            // 0..127
    if (tid >= NB * CO) return;
    int n = tid >> 6, co = tid & 63;
    float tl[10];
#pragma unroll
    for (int k = 0; k < 10; ++k) tl[k] = t[n * 10 + k];
    float l[5];
#pragma unroll
    for (int e = 0; e < 5; ++e) {
        int row = e * CO + co;
        float acc = gb[row];
#pragma unroll
        for (int k = 0; k < 10; ++k) acc += tl[k] * gw[row * 10 + k];
        l[e] = acc;
    }
    float m = l[0];
#pragma unroll
    for (int e = 1; e < 5; ++e) m = fmaxf(m, l[e]);
    float s = 0.f;
#pragma unroll
    for (int e = 0; e < 5; ++e) { l[e] = expf(l[e] - m); s += l[e]; }
    float inv = 1.f / s;
#pragma unroll
    for (int e = 0; e < 5; ++e) g[(n * 5 + e) * CO + co] = l[e] * inv;
}

// --------------------------------------------------------------- synth ----
// wbuf layout (bf16): [n][dz(5)][cich(CI/32)][t(25)][co(64)][cil(32)]
template <int CI>
__global__ void synth_kernel(const float* __restrict__ g,
                             const float* __restrict__ c5, const float* __restrict__ c3,
                             const float* __restrict__ c1, const float* __restrict__ a3,
                             const float* __restrict__ a5, unsigned short* __restrict__ wbuf) {
    int idx = blockIdx.x * 256 + threadIdx.x;
    constexpr int TOTAL = NB * CO * CI * 125;
    if (idx >= TOTAL) return;
    int tap = idx % 125;
    int ci  = (idx / 125) % CI;
    int co  = (idx / (125 * CI)) % CO;
    int n   = idx / (125 * CI * CO);
    const float* gn = g + n * 5 * CO;
    float g0 = gn[0 * CO + co], g1 = gn[1 * CO + co], g2 = gn[2 * CO + co],
          g3 = gn[3 * CO + co], g4 = gn[4 * CO + co];
    int dz = tap / 25, dy = (tap / 5) % 5, dx = tap % 5;
    int oc = co * CI + ci;
    float v = g0 * c5[(size_t)oc * 125 + tap] + g4 * a5[oc] * (1.f / 125.f);
    if (dz >= 1 && dz <= 3 && dy >= 1 && dy <= 3 && dx >= 1 && dx <= 3)
        v += g1 * c3[(size_t)oc * 27 + (dz - 1) * 9 + (dy - 1) * 3 + (dx - 1)]
           + g3 * a3[oc] * (1.f / 27.f);
    if (dz == 2 && dy == 2 && dx == 2) v += g2 * c1[oc];
    int t = (dy * 5 + dx);
    int cich = ci >> 5, cil = ci & 31;
    wbuf[((((size_t)(n * 5 + dz) * (CI / 32) + cich) * 25 + t) * 64 + co) * 32 + cil] = f2bf(v);
}

// ----------------------------------------------------------- MFMA conv ----
// Block: (n, z, yt, xt) -> 64co x (16y x 16x) output tile.
// Loop (dz, cich): stage bf16 plane [20][20][32] (XOR-swizzled) into LDS,
// then 25 taps x 16 mfma_f32_16x16x32_bf16 per wave.
// IN_F32: input is f32 NCDHW (converted in staging); else bf16 channel-last
// [n][z][y][x][CI]. OUT_CL: output bf16 channel-last; else f32 NCDHW.
template <int CI, bool IN_F32, bool OUT_CL>
__global__ __launch_bounds__(256, 2) void conv5_mfma(const void* __restrict__ xin_,
                                                     const unsigned short* __restrict__ wbuf,
                                                     void* __restrict__ outp) {
    constexpr int NCH = CI / 32;
    constexpr int NS  = 5 * NCH;
    __shared__ __align__(16) unsigned short lds[2][12800];   // 2 x 25.6 KB

    const int b   = blockIdx.x;
    const int xt  = b & 3;
    const int yt  = (b >> 2) & 3;
    const int z   = (b >> 4) & 63;
    const int n   = b >> 10;
    const int tid = threadIdx.x;
    const int lane = tid & 63, w = tid >> 6;
    const int xl = lane & 15, kh = lane >> 4;

    f32x4 acc[4][4];
#pragma unroll
    for (int pt = 0; pt < 4; ++pt)
#pragma unroll
        for (int c = 0; c < 4; ++c)
#pragma unroll
            for (int j = 0; j < 4; ++j) acc[pt][c][j] = 0.f;

    auto stage = [&](int s, unsigned short* dst) {
        int dz = s / NCH, cich = s % NCH;
        int zi = z + dz - 2;
        bool zok = (unsigned)zi < 64u;
#pragma unroll
        for (int r = 0; r < 7; ++r) {
            int idx = tid + r * 256;
            if (idx < 1600) {
                int khs = idx & 3;
                int p   = idx >> 2;          // 0..399
                int xx  = p % 20, yy = p / 20;
                int yi = yt * 16 - 2 + yy;
                int xi = xt * 16 - 2 + xx;
                bool ok = zok && (unsigned)yi < 64u && (unsigned)xi < 64u;
                uint4 v = make_uint4(0u, 0u, 0u, 0u);
                if (IN_F32) {
                    if (ok) {
                        const float* xp = (const float*)xin_
                            + (size_t)n * CI * SP + (size_t)(khs * 8) * SP
                            + (size_t)zi * 4096 + yi * 64 + xi;
                        float fv[8];
#pragma unroll
                        for (int i = 0; i < 8; ++i) fv[i] = xp[(size_t)i * SP];
                        v.x = pack2(fv[0], fv[1]); v.y = pack2(fv[2], fv[3]);
                        v.z = pack2(fv[4], fv[5]); v.w = pack2(fv[6], fv[7]);
                    }
                } else {
                    if (ok) {
                        const unsigned short* xp = (const unsigned short*)xin_
                            + ((size_t)(n * SP + zi * 4096 + yi * 64 + xi) * 64
                               + cich * 32 + khs * 8);
                        v = *(const uint4*)xp;
                    }
                }
                unsigned int off = ((unsigned)(yy * 20 + xx) * 64 + (unsigned)khs * 16)
                                   ^ ((unsigned)(xx & 3) << 4);
                *(uint4*)((char*)dst + off) = v;
            }
        }
    };

    auto compute = [&](int s, const unsigned short* src) {
        int dz = s / NCH, cich = s % NCH;
        const unsigned short* wp = wbuf
            + ((size_t)((n * 5 + dz) * NCH + cich) * 25) * 2048
            + (size_t)xl * 32 + kh * 8;
#pragma unroll 1
        for (int dy = 0; dy < 5; ++dy) {
#pragma unroll
            for (int dx = 0; dx < 5; ++dx) {
                int t = dy * 5 + dx;
                s16x8 a[4], bb[4];
#pragma unroll
                for (int c = 0; c < 4; ++c)
                    a[c] = *(const s16x8*)(wp + (size_t)t * 2048 + c * 512);
#pragma unroll
                for (int pt = 0; pt < 4; ++pt) {
                    int yy = w * 4 + pt + dy;
                    int xx = xl + dx;
                    unsigned int off = ((unsigned)(yy * 20 + xx) * 64 + (unsigned)kh * 16)
                                       ^ ((unsigned)(xx & 3) << 4);
                    bb[pt] = *(const s16x8*)((const char*)src + off);
                }
#pragma unroll
                for (int pt = 0; pt < 4; ++pt)
#pragma unroll
                    for (int c = 0; c < 4; ++c)
                        acc[pt][c] = __builtin_amdgcn_mfma_f32_16x16x32_bf16(
                            a[c], bb[pt], acc[pt][c], 0, 0, 0);
            }
        }
    };

    stage(0, lds[0]);
    __syncthreads();
#pragma unroll 1
    for (int s = 0; s < NS; ++s) {
        if (s + 1 < NS) stage(s + 1, lds[(s + 1) & 1]);
        compute(s, lds[s & 1]);
        __syncthreads();
    }

    if (OUT_CL) {
        // transpose 64co x 64px chunks through LDS, emit bf16 channel-last
        float* fl = (float*)&lds[0][0];    // 64 x 65 f32 = 16.6 KB
#pragma unroll 1
        for (int pt = 0; pt < 4; ++pt) {
#pragma unroll
            for (int c = 0; c < 4; ++c)
#pragma unroll
                for (int j = 0; j < 4; ++j)
                    fl[(c * 16 + kh * 4 + j) * 65 + w * 16 + xl] = acc[pt][c][j];
            __syncthreads();
            int px = tid >> 2, cq = tid & 3;
            int y = yt * 16 + (px >> 4) * 4 + pt;
            int x = xt * 16 + (px & 15);
            unsigned short* op = (unsigned short*)outp
                + ((size_t)(n * SP + z * 4096 + y * 64 + x) * 64 + cq * 16);
            unsigned int tmp[8];
#pragma unroll
            for (int q = 0; q < 8; ++q)
                tmp[q] = pack2(fl[(cq * 16 + 2 * q) * 65 + px],
                               fl[(cq * 16 + 2 * q + 1) * 65 + px]);
            *(uint4*)op       = make_uint4(tmp[0], tmp[1], tmp[2], tmp[3]);
            *(uint4*)(op + 8) = make_uint4(tmp[4], tmp[5], tmp[6], tmp[7]);
            __syncthreads();
        }
    } else {
        float* op = (float*)outp;
#pragma unroll
        for (int pt = 0; pt < 4; ++pt) {
            int y = yt * 16 + w * 4 + pt;
#pragma unroll
            for (int c = 0; c < 4; ++c)
#pragma unroll
                for (int j = 0; j < 4; ++j)
                    op[((size_t)(n * 64 + c * 16 + kh * 4 + j) * 64 + z) * 4096
                       + y * 64 + xt * 16 + xl] = acc[pt][c][j];
        }
    }
}

// ------------------------------------------------- stats (channel-last) ---
// h: bf16 [n][zyx][64]. Stage 1: 128 blocks (n x 64 chunks of 4096 zyx).
__global__ void stats_cl_kernel(const unsigned short* __restrict__ h,
                                float* __restrict__ part) {
    int blk = blockIdx.x;
    int n = blk >> 6, ch = blk & 63;
    int t = threadIdx.x;
    int co = t & 63, grp = t >> 6;
    const unsigned short* p = h + ((size_t)n * SP + (size_t)ch * 4096) * 64 + co;
    float s1 = 0.f, s2 = 0.f;
    for (int k = grp; k < 4096; k += 4) {
        float v = bf2f(p[(size_t)k * 64]);
        s1 += v; s2 += v * v;
    }
    __shared__ float sh1[4][64], sh2[4][64];
    sh1[grp][co] = s1; sh2[grp][co] = s2;
    __syncthreads();
    if (t < 64) {
        float a = sh1[0][t] + sh1[1][t] + sh1[2][t] + sh1[3][t];
        float b = sh2[0][t] + sh2[1][t] + sh2[2][t] + sh2[3][t];
        part[(size_t)blk * 128 + t]      = a;
        part[(size_t)blk * 128 + 64 + t] = b;
    }
}

__global__ void stats_fin_kernel(const float* __restrict__ part, float* __restrict__ st,
                                 int nchunk, float invS) {
    int t = threadIdx.x;
    if (t >= 128) return;
    int n = t >> 6, co = t & 63;
    float s1 = 0.f, s2 = 0.f;
    for (int ch = 0; ch < nchunk; ++ch) {
        s1 += part[(size_t)(n * 64 + ch) * 128 + co];
        s2 += part[(size_t)(n * 64 + ch) * 128 + 64 + co];
    }
    float mean = s1 * invS;
    float var  = s2 * invS - mean * mean;
    st[t * 2]     = mean;
    st[t * 2 + 1] = rsqrtf(var + 1e-5f);
}

// -------------------------------------- norm+mish in-place, channel-last --
__global__ void norm_mish_cl_kernel(unsigned short* __restrict__ h,
                                    const float* __restrict__ st,
                                    const float* __restrict__ gamma,
                                    const float* __restrict__ beta) {
    size_t idx = (size_t)blockIdx.x * 256 + threadIdx.x;   // over NB*SP*32 uints
    unsigned int* p = (unsigned int*)h;
    unsigned int v = p[idx];
    int c0 = ((int)(idx & 31)) * 2;
    size_t zyxn = idx >> 5;            // n*SP + zyx
    int n = (int)(zyxn >> 18);
    unsigned int out = 0;
#pragma unroll
    for (int hv = 0; hv < 2; ++hv) {
        int c = c0 + hv;
        int nc = n * 64 + c;
        float val = bf2f((unsigned short)((v >> (16 * hv)) & 0xffffu));
        float xh = (val - st[nc * 2]) * st[nc * 2 + 1] * gamma[c] + beta[c];
        float sp = (xh > 20.f) ? xh : log1pf(expf(xh));
        float th = 1.f - 2.f / (expf(2.f * sp) + 1.f);
        out |= ((unsigned int)f2bf(xh * th)) << (16 * hv);
    }
    p[idx] = out;
}

// --------------------------------------------------------------- stats ----
__global__ void stats_kernel(const float* __restrict__ in, float* __restrict__ stats, int S) {
    int nc = blockIdx.x;
    const float4* p = reinterpret_cast<const float4*>(in + (size_t)nc * S);
    float s = 0.f, s2 = 0.f;
    int S4 = S >> 2;
    for (int i = threadIdx.x; i < S4; i += 256) {
        float4 v = p[i];
        s  += v.x + v.y + v.z + v.w;
        s2 += v.x * v.x + v.y * v.y + v.z * v.z + v.w * v.w;
    }
    __shared__ float sh[256], sh2[256];
    sh[threadIdx.x] = s; sh2[threadIdx.x] = s2;
    __syncthreads();
    for (int o = 128; o > 0; o >>= 1) {
        if (threadIdx.x < o) {
            sh[threadIdx.x]  += sh[threadIdx.x + o];
            sh2[threadIdx.x] += sh2[threadIdx.x + o];
        }
        __syncthreads();
    }
    if (threadIdx.x == 0) {
        float mean = sh[0] / S;
        float var  = sh2[0] / S - mean * mean;
        stats[nc * 2]     = mean;
        stats[nc * 2 + 1] = rsqrtf(var + 1e-5f);
    }
}

// ----------------------------------------------------------- norm+mish ----
template <int SHIFT>
__global__ void norm_mish_kernel(float* __restrict__ buf, const float* __restrict__ stats,
                                 const float* __restrict__ gamma, const float* __restrict__ beta,
                                 int total4) {
    int idx = blockIdx.x * 256 + threadIdx.x;
    if (idx >= total4) return;
    float4 v = reinterpret_cast<float4*>(buf)[idx];
    int nc = idx >> (SHIFT - 2);
    int c  = nc & 63;
    float mean = stats[nc * 2], inv = stats[nc * 2 + 1];
    float ga = gamma[c], be = beta[c];
    float* pv = &v.x;
#pragma unroll
    for (int k = 0; k < 4; ++k) {
        float xh = (pv[k] - mean) * inv * ga + be;
        float sp = (xh > 20.f) ? xh : log1pf(expf(xh));
        float th = 1.f - 2.f / (expf(2.f * sp) + 1.f);
        pv[k] = xh * th;
    }
    reinterpret_cast<float4*>(buf)[idx] = v;
}

// ----------------------------------------------------------- down conv ----
__global__ __launch_bounds__(256) void down_conv_kernel(const float* __restrict__ xin,
                                                        const float* __restrict__ dw,
                                                        float* __restrict__ out) {
    __shared__ float ls[8][2][8][64];
    int b   = blockIdx.x;
    int yt  = b & 7;
    int z   = (b >> 3) & 31;
    int n   = b >> 8;
    int tid = threadIdx.x;
    int xo  = tid & 31;
    int cog = tid >> 5;

    float acc[4][8];
#pragma unroll
    for (int yo = 0; yo < 4; ++yo)
#pragma unroll
        for (int j = 0; j < 8; ++j) acc[yo][j] = 0.f;

    for (int cc = 0; cc < 8; ++cc) {
        for (int idx = tid; idx < 8192; idx += 256) {
            int xx = idx & 63;
            int yy = (idx >> 6) & 7;
            int dz = (idx >> 9) & 1;
            int c  = idx >> 10;
            ls[c][dz][yy][xx] = xin[((size_t)(n * CO + cc * 8 + c) * 64 + 2 * z + dz) * 4096
                                    + (yt * 8 + yy) * 64 + xx];
        }
        __syncthreads();
#pragma unroll 1
        for (int c = 0; c < 8; ++c) {
            int ci = cc * 8 + c;
#pragma unroll
            for (int tap = 0; tap < 8; ++tap) {
                int dz = tap >> 2, dy = (tap >> 1) & 1, dx = tap & 1;
                float w[8];
#pragma unroll
                for (int j = 0; j < 8; ++j)
                    w[j] = dw[((size_t)(cog * 8 + j) * CO + ci) * 8 + tap];
#pragma unroll
                for (int yo = 0; yo < 4; ++yo) {
                    float xv = ls[c][dz][yo * 2 + dy][2 * xo + dx];
#pragma unroll
                    for (int j = 0; j < 8; ++j) acc[yo][j] += w[j] * xv;
                }
            }
        }
        __syncthreads();
    }
#pragma unroll
    for (int yo = 0; yo < 4; ++yo)
#pragma unroll
        for (int j = 0; j < 8; ++j)
            out[((size_t)(n * CO + cog * 8 + j) * 32 + z) * 1024 + (yt * 4 + yo) * 32 + xo]
                = acc[yo][j];
}

// -------------------------------------------------------------- launch ----
extern "C" void kernel_launch(void* const* d_in, const int* in_sizes, int n_in,
                              void* d_out, int out_size, void* d_ws, size_t ws_size,
                              hipStream_t stream) {
    const float* x      = (const float*)d_in[0];
    const float* t      = (const float*)d_in[1];
    const float* l1_c5  = (const float*)d_in[2];
    const float* l1_c3  = (const float*)d_in[3];
    const float* l1_c1  = (const float*)d_in[4];
    const float* l1_a3  = (const float*)d_in[5];
    const float* l1_a5  = (const float*)d_in[6];
    const float* l1_gw  = (const float*)d_in[7];
    const float* l1_gb  = (const float*)d_in[8];
    const float* l1_ga  = (const float*)d_in[9];
    const float* l1_be  = (const float*)d_in[10];
    const float* l2_c5  = (const float*)d_in[11];
    const float* l2_c3  = (const float*)d_in[12];
    const float* l2_c1  = (const float*)d_in[13];
    const float* l2_a3  = (const float*)d_in[14];
    const float* l2_a5  = (const float*)d_in[15];
    const float* l2_gw  = (const float*)d_in[16];
    const float* l2_gb  = (const float*)d_in[17];
    const float* l2_ga  = (const float*)d_in[18];
    const float* l2_be  = (const float*)d_in[19];
    const float* down_w = (const float*)d_in[20];
    const float* dn_ga  = (const float*)d_in[21];
    const float* dn_be  = (const float*)d_in[22];

    char* ws = (char*)d_ws;
    unsigned short* h2 = (unsigned short*)(ws);                 // 67,108,864 B
    unsigned short* w1 = (unsigned short*)(ws + 67108864);      //  1,024,000 B
    unsigned short* w2 = (unsigned short*)(ws + 68132864);      //  2,048,000 B
    float* g1   = (float*)(ws + 70180864);                      //      2,560 B
    float* g2   = (float*)(ws + 70183424);                      //      2,560 B
    float* st   = (float*)(ws + 70185984);                      //      1,024 B
    float* part = (float*)(ws + 70187008);                      //     65,536 B

    float* yout  = (float*)d_out;          // (2,64,32,32,32)
    float* xskip = (float*)d_out + Y_SZ;   // (2,64,64,64,64)

    gate_kernel<<<1, 128, 0, stream>>>(t, l1_gw, l1_gb, g1);
    gate_kernel<<<1, 128, 0, stream>>>(t, l2_gw, l2_gb, g2);
    synth_kernel<32><<<(NB * CO * 32 * 125 + 255) / 256, 256, 0, stream>>>(
        g1, l1_c5, l1_c3, l1_c1, l1_a3, l1_a5, w1);
    synth_kernel<64><<<(NB * CO * 64 * 125 + 255) / 256, 256, 0, stream>>>(
        g2, l2_c5, l2_c3, l2_c1, l2_a3, l2_a5, w2);

    // layer 1: MFMA conv (f32 NCDHW in -> bf16 channel-last raw out)
    conv5_mfma<32, true, true><<<2048, 256, 0, stream>>>(x, w1, h2);
    stats_cl_kernel<<<128, 256, 0, stream>>>(h2, part);
    stats_fin_kernel<<<1, 128, 0, stream>>>(part, st, 64, 1.f / SP);
    norm_mish_cl_kernel<<<65536, 256, 0, stream>>>(h2, st, l1_ga, l1_be);

    // layer 2: MFMA conv (bf16 channel-last in -> f32 NCDHW raw into x_skip)
    conv5_mfma<64, false, false><<<2048, 256, 0, stream>>>(h2, w2, xskip);
    stats_kernel<<<NC, 256, 0, stream>>>(xskip, st, SP);
    norm_mish_kernel<18><<<(NC * SP / 4 + 255) / 256, 256, 0, stream>>>(
        xskip, st, l2_ga, l2_be, NC * SP / 4);

    // downsample
    down_conv_kernel<<<NB * 32 * 8, 256, 0, stream>>>(xskip, down_w, yout);
    stats_kernel<<<NC, 256, 0, stream>>>(yout, st, 32768);
    norm_mish_kernel<15><<<(NC * 32768 / 4 + 255) / 256, 256, 0, stream>>>(
        yout, st, dn_ga, dn_be, NC * 32768 / 4);
}

// Round 3
// 1180.304 us; speedup vs baseline: 11.2426x; 1.6255x over previous
//
#include <hip/hip_runtime.h>
#include <cstdint>
#include <cstddef>

constexpr int NB  = 2;
constexpr int CO  = 64;
constexpr int DIM = 64;
constexpr int SP  = DIM * DIM * DIM;       // 262144
constexpr int NC  = NB * CO;               // 128
constexpr int Y_SZ = NB * CO * 32 * 32 * 32;

typedef float f32x4 __attribute__((ext_vector_type(4)));
typedef short s16x8 __attribute__((ext_vector_type(8)));

__device__ __forceinline__ unsigned short f2bf(float f) {
    unsigned int u = __float_as_uint(f);
    unsigned int r = (u + 0x7fffu + ((u >> 16) & 1u)) >> 16;
    return (unsigned short)r;
}
__device__ __forceinline__ float bf2f(unsigned short u) {
    return __uint_as_float((unsigned int)u << 16);
}
__device__ __forceinline__ unsigned int pack2(float a, float b) {
    return (unsigned int)f2bf(a) | ((unsigned int)f2bf(b) << 16);
}
// mish(x) = x * tanh(softplus(x)) = x*(e^2+2e)/(e^2+2e+2), e = exp(x)
__device__ __forceinline__ float mish_f(float x) {
    float e = __expf(x);
    float num = e * (e + 2.f);
    float r = x * num * __builtin_amdgcn_rcpf(num + 2.f);
    return (x > 15.f) ? x : r;
}

// ---------------------------------------------------------------- gate ----
__global__ void gate_kernel(const float* __restrict__ t, const float* __restrict__ gw,
                            const float* __restrict__ gb, float* __restrict__ g) {
    int tid = threadIdx.x;
    if (tid >= NB * CO) return;
    int n = tid >> 6, co = tid & 63;
    float tl[10];
#pragma unroll
    for (int k = 0; k < 10; ++k) tl[k] = t[n * 10 + k];
    float l[5];
#pragma unroll
    for (int e = 0; e < 5; ++e) {
        int row = e * CO + co;
        float acc = gb[row];
#pragma unroll
        for (int k = 0; k < 10; ++k) acc += tl[k] * gw[row * 10 + k];
        l[e] = acc;
    }
    float m = l[0];
#pragma unroll
    for (int e = 1; e < 5; ++e) m = fmaxf(m, l[e]);
    float s = 0.f;
#pragma unroll
    for (int e = 0; e < 5; ++e) { l[e] = expf(l[e] - m); s += l[e]; }
    float inv = 1.f / s;
#pragma unroll
    for (int e = 0; e < 5; ++e) g[(n * 5 + e) * CO + co] = l[e] * inv;
}

// --------------------------------------------------------------- synth ----
// wbuf (bf16): [n][dz(5)][cich(CI/32)][t(25)][co(64)][cil(32)]
template <int CI>
__global__ void synth_kernel(const float* __restrict__ g,
                             const float* __restrict__ c5, const float* __restrict__ c3,
                             const float* __restrict__ c1, const float* __restrict__ a3,
                             const float* __restrict__ a5, unsigned short* __restrict__ wbuf) {
    int idx = blockIdx.x * 256 + threadIdx.x;
    constexpr int TOTAL = NB * CO * CI * 125;
    if (idx >= TOTAL) return;
    int tap = idx % 125;
    int ci  = (idx / 125) % CI;
    int co  = (idx / (125 * CI)) % CO;
    int n   = idx / (125 * CI * CO);
    const float* gn = g + n * 5 * CO;
    float g0 = gn[0 * CO + co], g1 = gn[1 * CO + co], g2 = gn[2 * CO + co],
          g3 = gn[3 * CO + co], g4 = gn[4 * CO + co];
    int dz = tap / 25, dy = (tap / 5) % 5, dx = tap % 5;
    int oc = co * CI + ci;
    float v = g0 * c5[(size_t)oc * 125 + tap] + g4 * a5[oc] * (1.f / 125.f);
    if (dz >= 1 && dz <= 3 && dy >= 1 && dy <= 3 && dx >= 1 && dx <= 3)
        v += g1 * c3[(size_t)oc * 27 + (dz - 1) * 9 + (dy - 1) * 3 + (dx - 1)]
           + g3 * a3[oc] * (1.f / 27.f);
    if (dz == 2 && dy == 2 && dx == 2) v += g2 * c1[oc];
    int t = (dy * 5 + dx);
    int cich = ci >> 5, cil = ci & 31;
    wbuf[((((size_t)(n * 5 + dz) * (CI / 32) + cich) * 25 + t) * 64 + co) * 32 + cil] = f2bf(v);
}

// -------------------------------------------------------------- x->CL -----
// f32 NCDHW (n,32,zyx) -> bf16 channel-last [n][zyx][32]
__global__ __launch_bounds__(256) void x_to_cl(const float* __restrict__ x,
                                               unsigned short* __restrict__ xcl) {
    __shared__ float ld[32][256];
    int b = blockIdx.x;                   // 2048 = n(2) x 1024
    int n = b >> 10;
    size_t base = (size_t)(b & 1023) * 256;
    int tid = threadIdx.x;
    const float* xp = x + (size_t)n * 32 * SP + base + tid;
#pragma unroll
    for (int c = 0; c < 32; ++c) ld[c][tid] = xp[(size_t)c * SP];
    __syncthreads();
    uint4* op = (uint4*)(xcl + ((size_t)n * SP + base) * 32);
#pragma unroll
    for (int r = 0; r < 4; ++r) {
        int idx = r * 256 + tid;
        int px = idx >> 2, q = idx & 3;
        uint4 o;
        o.x = pack2(ld[q * 8 + 0][px], ld[q * 8 + 1][px]);
        o.y = pack2(ld[q * 8 + 2][px], ld[q * 8 + 3][px]);
        o.z = pack2(ld[q * 8 + 4][px], ld[q * 8 + 5][px]);
        o.w = pack2(ld[q * 8 + 6][px], ld[q * 8 + 7][px]);
        op[idx] = o;
    }
}

// ----------------------------------------------------------- MFMA conv ----
// Input: bf16 channel-last [n][zyx][CI]. Per block: (n,z,yt,xt) -> 64co x 16y x 16x.
// Fused IN-stats partials written to part[block][128] (64 sum + 64 sumsq).
template <int CI, bool OUT_CL>
__global__ __launch_bounds__(256, 2) void conv5_mfma(const unsigned short* __restrict__ xin,
                                                     const unsigned short* __restrict__ wbuf,
                                                     void* __restrict__ outp,
                                                     float* __restrict__ part) {
    constexpr int NCH = CI / 32;
    constexpr int NS  = 5 * NCH;
    __shared__ __align__(16) unsigned short lds[2][12800];

    const int b   = blockIdx.x;
    const int xt  = b & 3;
    const int yt  = (b >> 2) & 3;
    const int z   = (b >> 4) & 63;
    const int n   = b >> 10;
    const int tid = threadIdx.x;
    const int lane = tid & 63, w = tid >> 6;
    const int xl = lane & 15, kh = lane >> 4;

    f32x4 acc[4][4];
#pragma unroll
    for (int pt = 0; pt < 4; ++pt)
#pragma unroll
        for (int c = 0; c < 4; ++c)
#pragma unroll
            for (int j = 0; j < 4; ++j) acc[pt][c][j] = 0.f;

    auto stage = [&](int s, unsigned short* dst) {
        int dz = s / NCH, cich = s % NCH;
        int zi = z + dz - 2;
        bool zok = (unsigned)zi < 64u;
#pragma unroll
        for (int r = 0; r < 7; ++r) {
            int idx = tid + r * 256;
            if (idx < 1600) {
                int khs = idx & 3;
                int p   = idx >> 2;
                int xx  = p % 20, yy = p / 20;
                int yi = yt * 16 - 2 + yy;
                int xi = xt * 16 - 2 + xx;
                bool ok = zok && (unsigned)yi < 64u && (unsigned)xi < 64u;
                uint4 v = make_uint4(0u, 0u, 0u, 0u);
                if (ok) {
                    const unsigned short* xp = xin
                        + ((size_t)(n * SP + zi * 4096 + yi * 64 + xi) * CI
                           + cich * 32 + khs * 8);
                    v = *(const uint4*)xp;
                }
                unsigned int off = ((unsigned)(yy * 20 + xx) * 64 + (unsigned)khs * 16)
                                   ^ ((unsigned)(xx & 3) << 4);
                *(uint4*)((char*)dst + off) = v;
            }
        }
    };

    auto compute = [&](int s, const unsigned short* src) {
        int dz = s / NCH, cich = s % NCH;
        const unsigned short* wp = wbuf
            + ((size_t)((n * 5 + dz) * NCH + cich) * 25) * 2048
            + (size_t)xl * 32 + kh * 8;
#pragma unroll 1
        for (int dx = 0; dx < 5; ++dx) {
            int xx = xl + dx;
            s16x8 fr[8];
#pragma unroll
            for (int r = 0; r < 8; ++r) {
                int yy = w * 4 + r;
                unsigned int off = ((unsigned)(yy * 20 + xx) * 64 + (unsigned)kh * 16)
                                   ^ ((unsigned)(xx & 3) << 4);
                fr[r] = *(const s16x8*)((const char*)src + off);
            }
#pragma unroll
            for (int dy = 0; dy < 5; ++dy) {
                int t = dy * 5 + dx;
                s16x8 a[4];
#pragma unroll
                for (int c = 0; c < 4; ++c)
                    a[c] = *(const s16x8*)(wp + (size_t)t * 2048 + c * 512);
#pragma unroll
                for (int pt = 0; pt < 4; ++pt)
#pragma unroll
                    for (int c = 0; c < 4; ++c)
                        acc[pt][c] = __builtin_amdgcn_mfma_f32_16x16x32_bf16(
                            a[c], fr[pt + dy], acc[pt][c], 0, 0, 0);
            }
        }
    };

    stage(0, lds[0]);
    __syncthreads();
#pragma unroll 1
    for (int s = 0; s < NS; ++s) {
        if (s + 1 < NS) stage(s + 1, lds[(s + 1) & 1]);
        compute(s, lds[s & 1]);
        __syncthreads();
    }

    // ---- fused instance-norm partial sums (per block, per co) ----
    {
        float s1v[4][4], s2v[4][4];
#pragma unroll
        for (int c = 0; c < 4; ++c)
#pragma unroll
            for (int j = 0; j < 4; ++j) {
                float a0 = acc[0][c][j], a1 = acc[1][c][j],
                      a2 = acc[2][c][j], a3 = acc[3][c][j];
                s1v[c][j] = (a0 + a1) + (a2 + a3);
                s2v[c][j] = (a0 * a0 + a1 * a1) + (a2 * a2 + a3 * a3);
            }
#pragma unroll
        for (int o = 1; o < 16; o <<= 1) {
#pragma unroll
            for (int c = 0; c < 4; ++c)
#pragma unroll
                for (int j = 0; j < 4; ++j) {
                    s1v[c][j] += __shfl_xor(s1v[c][j], o, 64);
                    s2v[c][j] += __shfl_xor(s2v[c][j], o, 64);
                }
        }
        float* sh1 = (float*)&lds[1][0];      // [4][64]
        float* sh2 = sh1 + 256;
        if (xl == 0) {
#pragma unroll
            for (int c = 0; c < 4; ++c)
#pragma unroll
                for (int j = 0; j < 4; ++j) {
                    sh1[w * 64 + c * 16 + kh * 4 + j] = s1v[c][j];
                    sh2[w * 64 + c * 16 + kh * 4 + j] = s2v[c][j];
                }
        }
        __syncthreads();
        if (tid < 64) {
            float a = sh1[tid] + sh1[64 + tid] + sh1[128 + tid] + sh1[192 + tid];
            float q = sh2[tid] + sh2[64 + tid] + sh2[128 + tid] + sh2[192 + tid];
            part[(size_t)b * 128 + tid]      = a;
            part[(size_t)b * 128 + 64 + tid] = q;
        }
    }

    if (OUT_CL) {
        float* fl = (float*)&lds[0][0];       // 64 x 65 f32
#pragma unroll 1
        for (int pt = 0; pt < 4; ++pt) {
#pragma unroll
            for (int c = 0; c < 4; ++c)
#pragma unroll
                for (int j = 0; j < 4; ++j)
                    fl[(c * 16 + kh * 4 + j) * 65 + w * 16 + xl] = acc[pt][c][j];
            __syncthreads();
            int px = tid >> 2, cq = tid & 3;
            int y = yt * 16 + (px >> 4) * 4 + pt;
            int x = xt * 16 + (px & 15);
            unsigned short* op = (unsigned short*)outp
                + ((size_t)(n * SP + z * 4096 + y * 64 + x) * 64 + cq * 16);
            unsigned int tmp[8];
#pragma unroll
            for (int q = 0; q < 8; ++q)
                tmp[q] = pack2(fl[(cq * 16 + 2 * q) * 65 + px],
                               fl[(cq * 16 + 2 * q + 1) * 65 + px]);
            *(uint4*)op       = make_uint4(tmp[0], tmp[1], tmp[2], tmp[3]);
            *(uint4*)(op + 8) = make_uint4(tmp[4], tmp[5], tmp[6], tmp[7]);
            __syncthreads();
        }
    } else {
        float* op = (float*)outp;
#pragma unroll
        for (int pt = 0; pt < 4; ++pt) {
            int y = yt * 16 + w * 4 + pt;
#pragma unroll
            for (int c = 0; c < 4; ++c)
#pragma unroll
                for (int j = 0; j < 4; ++j)
                    op[((size_t)(n * 64 + c * 16 + kh * 4 + j) * 64 + z) * 4096
                       + y * 64 + xt * 16 + xl] = acc[pt][c][j];
        }
    }
}

// ------------------------------------------------- stats finalize ---------
// part: [2048][128] (1024 blocks per n). grid = 2 (n), 256 threads.
__global__ void stats_fin_conv(const float* __restrict__ part, float* __restrict__ st) {
    int n = blockIdx.x;
    int t = threadIdx.x;
    int co = t & 63, q = t >> 6;
    float s1 = 0.f, s2 = 0.f;
    for (int bb = q * 256; bb < q * 256 + 256; ++bb) {
        const float* p = part + (size_t)(n * 1024 + bb) * 128;
        s1 += p[co];
        s2 += p[64 + co];
    }
    __shared__ float sh1[4][64], sh2[4][64];
    sh1[q][co] = s1; sh2[q][co] = s2;
    __syncthreads();
    if (t < 64) {
        float a = sh1[0][t] + sh1[1][t] + sh1[2][t] + sh1[3][t];
        float b = sh2[0][t] + sh2[1][t] + sh2[2][t] + sh2[3][t];
        float mean = a * (1.f / SP);
        float var  = b * (1.f / SP) - mean * mean;
        st[(n * 64 + t) * 2]     = mean;
        st[(n * 64 + t) * 2 + 1] = rsqrtf(var + 1e-5f);
    }
}

// -------------------------------------- norm+mish in-place, channel-last --
// h: bf16 [n][zyx][64]; one uint4 (8 channels) per thread.
__global__ void norm_mish_cl_kernel(unsigned short* __restrict__ h,
                                    const float* __restrict__ st,
                                    const float* __restrict__ gamma,
                                    const float* __restrict__ beta) {
    size_t idx = (size_t)blockIdx.x * 256 + threadIdx.x;   // NB*SP*8 items
    uint4 v = ((uint4*)h)[idx];
    int c0 = ((int)(idx & 7)) * 8;
    size_t pix = idx >> 3;
    int n = (int)(pix >> 18);
    unsigned int* pv = &v.x;
#pragma unroll
    for (int q = 0; q < 4; ++q) {
        unsigned int wv = pv[q];
        unsigned int out = 0;
#pragma unroll
        for (int hv = 0; hv < 2; ++hv) {
            int c = c0 + 2 * q + hv;
            int nc = n * 64 + c;
            float val = bf2f((unsigned short)((wv >> (16 * hv)) & 0xffffu));
            float xh = (val - st[nc * 2]) * st[nc * 2 + 1] * gamma[c] + beta[c];
            out |= ((unsigned int)f2bf(mish_f(xh))) << (16 * hv);
        }
        pv[q] = out;
    }
    ((uint4*)h)[idx] = v;
}

// --------------------------------------------------------------- stats ----
__global__ void stats_kernel(const float* __restrict__ in, float* __restrict__ stats, int S) {
    int nc = blockIdx.x;
    const float4* p = reinterpret_cast<const float4*>(in + (size_t)nc * S);
    float s = 0.f, s2 = 0.f;
    int S4 = S >> 2;
    for (int i = threadIdx.x; i < S4; i += 256) {
        float4 v = p[i];
        s  += v.x + v.y + v.z + v.w;
        s2 += v.x * v.x + v.y * v.y + v.z * v.z + v.w * v.w;
    }
    __shared__ float sh[256], sh2[256];
    sh[threadIdx.x] = s; sh2[threadIdx.x] = s2;
    __syncthreads();
    for (int o = 128; o > 0; o >>= 1) {
        if (threadIdx.x < o) {
            sh[threadIdx.x]  += sh[threadIdx.x + o];
            sh2[threadIdx.x] += sh2[threadIdx.x + o];
        }
        __syncthreads();
    }
    if (threadIdx.x == 0) {
        float mean = sh[0] / S;
        float var  = sh2[0] / S - mean * mean;
        stats[nc * 2]     = mean;
        stats[nc * 2 + 1] = rsqrtf(var + 1e-5f);
    }
}

// ----------------------------------------------------------- norm+mish ----
template <int SHIFT>
__global__ void norm_mish_kernel(float* __restrict__ buf, const float* __restrict__ stats,
                                 const float* __restrict__ gamma, const float* __restrict__ beta,
                                 int total4) {
    int idx = blockIdx.x * 256 + threadIdx.x;
    if (idx >= total4) return;
    float4 v = reinterpret_cast<float4*>(buf)[idx];
    int nc = idx >> (SHIFT - 2);
    int c  = nc & 63;
    float mean = stats[nc * 2], inv = stats[nc * 2 + 1];
    float ga = gamma[c], be = beta[c];
    float* pv = &v.x;
#pragma unroll
    for (int k = 0; k < 4; ++k) {
        float xh = (pv[k] - mean) * inv * ga + be;
        pv[k] = mish_f(xh);
    }
    reinterpret_cast<float4*>(buf)[idx] = v;
}

// ----------------------------------------------------------- down conv ----
__global__ __launch_bounds__(256) void down_conv_kernel(const float* __restrict__ xin,
                                                        const float* __restrict__ dw,
                                                        float* __restrict__ out) {
    __shared__ float ls[8][2][8][64];
    int b   = blockIdx.x;
    int yt  = b & 7;
    int z   = (b >> 3) & 31;
    int n   = b >> 8;
    int tid = threadIdx.x;
    int xo  = tid & 31;
    int cog = tid >> 5;

    float acc[4][8];
#pragma unroll
    for (int yo = 0; yo < 4; ++yo)
#pragma unroll
        for (int j = 0; j < 8; ++j) acc[yo][j] = 0.f;

    for (int cc = 0; cc < 8; ++cc) {
        for (int idx = tid; idx < 8192; idx += 256) {
            int xx = idx & 63;
            int yy = (idx >> 6) & 7;
            int dz = (idx >> 9) & 1;
            int c  = idx >> 10;
            ls[c][dz][yy][xx] = xin[((size_t)(n * CO + cc * 8 + c) * 64 + 2 * z + dz) * 4096
                                    + (yt * 8 + yy) * 64 + xx];
        }
        __syncthreads();
#pragma unroll 1
        for (int c = 0; c < 8; ++c) {
            int ci = cc * 8 + c;
#pragma unroll
            for (int tap = 0; tap < 8; ++tap) {
                int dz = tap >> 2, dy = (tap >> 1) & 1, dx = tap & 1;
                float w[8];
#pragma unroll
                for (int j = 0; j < 8; ++j)
                    w[j] = dw[((size_t)(cog * 8 + j) * CO + ci) * 8 + tap];
#pragma unroll
                for (int yo = 0; yo < 4; ++yo) {
                    float xv = ls[c][dz][yo * 2 + dy][2 * xo + dx];
#pragma unroll
                    for (int j = 0; j < 8; ++j) acc[yo][j] += w[j] * xv;
                }
            }
        }
        __syncthreads();
    }
#pragma unroll
    for (int yo = 0; yo < 4; ++yo)
#pragma unroll
        for (int j = 0; j < 8; ++j)
            out[((size_t)(n * CO + cog * 8 + j) * 32 + z) * 1024 + (yt * 4 + yo) * 32 + xo]
                = acc[yo][j];
}

// -------------------------------------------------------------- launch ----
extern "C" void kernel_launch(void* const* d_in, const int* in_sizes, int n_in,
                              void* d_out, int out_size, void* d_ws, size_t ws_size,
                              hipStream_t stream) {
    const float* x      = (const float*)d_in[0];
    const float* t      = (const float*)d_in[1];
    const float* l1_c5  = (const float*)d_in[2];
    const float* l1_c3  = (const float*)d_in[3];
    const float* l1_c1  = (const float*)d_in[4];
    const float* l1_a3  = (const float*)d_in[5];
    const float* l1_a5  = (const float*)d_in[6];
    const float* l1_gw  = (const float*)d_in[7];
    const float* l1_gb  = (const float*)d_in[8];
    const float* l1_ga  = (const float*)d_in[9];
    const float* l1_be  = (const float*)d_in[10];
    const float* l2_c5  = (const float*)d_in[11];
    const float* l2_c3  = (const float*)d_in[12];
    const float* l2_c1  = (const float*)d_in[13];
    const float* l2_a3  = (const float*)d_in[14];
    const float* l2_a5  = (const float*)d_in[15];
    const float* l2_gw  = (const float*)d_in[16];
    const float* l2_gb  = (const float*)d_in[17];
    const float* l2_ga  = (const float*)d_in[18];
    const float* l2_be  = (const float*)d_in[19];
    const float* down_w = (const float*)d_in[20];
    const float* dn_ga  = (const float*)d_in[21];
    const float* dn_be  = (const float*)d_in[22];

    char* ws = (char*)d_ws;
    unsigned short* xcl = (unsigned short*)(ws);                  // 33,554,432 B
    unsigned short* h2  = (unsigned short*)(ws + 33554432);       // 67,108,864 B
    unsigned short* w1  = (unsigned short*)(ws + 100663296);      //  1,024,000 B
    unsigned short* w2  = (unsigned short*)(ws + 101687296);      //  2,048,000 B
    float* g1    = (float*)(ws + 103735296);                      //      2,560 B
    float* g2    = (float*)(ws + 103737856);                      //      2,560 B
    float* st1   = (float*)(ws + 103740416);                      //      1,024 B
    float* st2   = (float*)(ws + 103741440);                      //      1,024 B
    float* st3   = (float*)(ws + 103742464);                      //      1,024 B
    float* part1 = (float*)(ws + 103743488);                      //  1,048,576 B
    float* part2 = (float*)(ws + 104792064);                      //  1,048,576 B

    float* yout  = (float*)d_out;
    float* xskip = (float*)d_out + Y_SZ;

    gate_kernel<<<1, 128, 0, stream>>>(t, l1_gw, l1_gb, g1);
    gate_kernel<<<1, 128, 0, stream>>>(t, l2_gw, l2_gb, g2);
    synth_kernel<32><<<(NB * CO * 32 * 125 + 255) / 256, 256, 0, stream>>>(
        g1, l1_c5, l1_c3, l1_c1, l1_a3, l1_a5, w1);
    synth_kernel<64><<<(NB * CO * 64 * 125 + 255) / 256, 256, 0, stream>>>(
        g2, l2_c5, l2_c3, l2_c1, l2_a3, l2_a5, w2);
    x_to_cl<<<2048, 256, 0, stream>>>(x, xcl);

    // layer 1
    conv5_mfma<32, true><<<2048, 256, 0, stream>>>(xcl, w1, h2, part1);
    stats_fin_conv<<<2, 256, 0, stream>>>(part1, st1);
    norm_mish_cl_kernel<<<16384, 256, 0, stream>>>(h2, st1, l1_ga, l1_be);

    // layer 2
    conv5_mfma<64, false><<<2048, 256, 0, stream>>>(h2, w2, xskip, part2);
    stats_fin_conv<<<2, 256, 0, stream>>>(part2, st2);
    norm_mish_kernel<18><<<(NC * SP / 4 + 255) / 256, 256, 0, stream>>>(
        xskip, st2, l2_ga, l2_be, NC * SP / 4);

    // downsample
    down_conv_kernel<<<NB * 32 * 8, 256, 0, stream>>>(xskip, down_w, yout);
    stats_kernel<<<NC, 256, 0, stream>>>(yout, st3, 32768);
    norm_mish_kernel<15><<<(NC * 32768 / 4 + 255) / 256, 256, 0, stream>>>(
        yout, st3, dn_ga, dn_be, NC * 32768 / 4);
}

// Round 4
// 1136.626 us; speedup vs baseline: 11.6747x; 1.0384x over previous
//
#include <hip/hip_runtime.h>
#include <cstdint>
#include <cstddef>

constexpr int NB  = 2;
constexpr int CO  = 64;
constexpr int DIM = 64;
constexpr int SP  = DIM * DIM * DIM;       // 262144
constexpr int NC  = NB * CO;               // 128
constexpr int Y_SZ = NB * CO * 32 * 32 * 32;

typedef float f32x4 __attribute__((ext_vector_type(4)));
typedef short s16x8 __attribute__((ext_vector_type(8)));

__device__ __forceinline__ unsigned short f2bf(float f) {
    unsigned int u = __float_as_uint(f);
    unsigned int r = (u + 0x7fffu + ((u >> 16) & 1u)) >> 16;
    return (unsigned short)r;
}
__device__ __forceinline__ float bf2f(unsigned short u) {
    return __uint_as_float((unsigned int)u << 16);
}
__device__ __forceinline__ unsigned int pack2(float a, float b) {
    return (unsigned int)f2bf(a) | ((unsigned int)f2bf(b) << 16);
}
// mish(x) = x * tanh(softplus(x)) = x*(e^2+2e)/(e^2+2e+2), e = exp(x)
__device__ __forceinline__ float mish_f(float x) {
    float e = __expf(x);
    float num = e * (e + 2.f);
    float r = x * num * __builtin_amdgcn_rcpf(num + 2.f);
    return (x > 15.f) ? x : r;
}

// ---------------------------------------------------------------- gate ----
__global__ void gate_kernel(const float* __restrict__ t, const float* __restrict__ gw,
                            const float* __restrict__ gb, float* __restrict__ g) {
    int tid = threadIdx.x;
    if (tid >= NB * CO) return;
    int n = tid >> 6, co = tid & 63;
    float tl[10];
#pragma unroll
    for (int k = 0; k < 10; ++k) tl[k] = t[n * 10 + k];
    float l[5];
#pragma unroll
    for (int e = 0; e < 5; ++e) {
        int row = e * CO + co;
        float acc = gb[row];
#pragma unroll
        for (int k = 0; k < 10; ++k) acc += tl[k] * gw[row * 10 + k];
        l[e] = acc;
    }
    float m = l[0];
#pragma unroll
    for (int e = 1; e < 5; ++e) m = fmaxf(m, l[e]);
    float s = 0.f;
#pragma unroll
    for (int e = 0; e < 5; ++e) { l[e] = expf(l[e] - m); s += l[e]; }
    float inv = 1.f / s;
#pragma unroll
    for (int e = 0; e < 5; ++e) g[(n * 5 + e) * CO + co] = l[e] * inv;
}

// --------------------------------------------------------------- synth ----
// wbuf (bf16): [n][dz(5)][cich(CI/32)][t(25)][co(64)][cil(32)]
template <int CI>
__global__ void synth_kernel(const float* __restrict__ g,
                             const float* __restrict__ c5, const float* __restrict__ c3,
                             const float* __restrict__ c1, const float* __restrict__ a3,
                             const float* __restrict__ a5, unsigned short* __restrict__ wbuf) {
    int idx = blockIdx.x * 256 + threadIdx.x;
    constexpr int TOTAL = NB * CO * CI * 125;
    if (idx >= TOTAL) return;
    int tap = idx % 125;
    int ci  = (idx / 125) % CI;
    int co  = (idx / (125 * CI)) % CO;
    int n   = idx / (125 * CI * CO);
    const float* gn = g + n * 5 * CO;
    float g0 = gn[0 * CO + co], g1 = gn[1 * CO + co], g2 = gn[2 * CO + co],
          g3 = gn[3 * CO + co], g4 = gn[4 * CO + co];
    int dz = tap / 25, dy = (tap / 5) % 5, dx = tap % 5;
    int oc = co * CI + ci;
    float v = g0 * c5[(size_t)oc * 125 + tap] + g4 * a5[oc] * (1.f / 125.f);
    if (dz >= 1 && dz <= 3 && dy >= 1 && dy <= 3 && dx >= 1 && dx <= 3)
        v += g1 * c3[(size_t)oc * 27 + (dz - 1) * 9 + (dy - 1) * 3 + (dx - 1)]
           + g3 * a3[oc] * (1.f / 27.f);
    if (dz == 2 && dy == 2 && dx == 2) v += g2 * c1[oc];
    int t = (dy * 5 + dx);
    int cich = ci >> 5, cil = ci & 31;
    wbuf[((((size_t)(n * 5 + dz) * (CI / 32) + cich) * 25 + t) * 64 + co) * 32 + cil] = f2bf(v);
}

// -------------------------------------------------------------- x->CL -----
// f32 NCDHW (n,32,zyx) -> bf16 channel-last [n][zyx][32]
__global__ __launch_bounds__(256) void x_to_cl(const float* __restrict__ x,
                                               unsigned short* __restrict__ xcl) {
    __shared__ float ld[32][256];
    int b = blockIdx.x;                   // 2048 = n(2) x 1024
    int n = b >> 10;
    size_t base = (size_t)(b & 1023) * 256;
    int tid = threadIdx.x;
    const float* xp = x + (size_t)n * 32 * SP + base + tid;
#pragma unroll
    for (int c = 0; c < 32; ++c) ld[c][tid] = xp[(size_t)c * SP];
    __syncthreads();
    uint4* op = (uint4*)(xcl + ((size_t)n * SP + base) * 32);
#pragma unroll
    for (int r = 0; r < 4; ++r) {
        int idx = r * 256 + tid;
        int px = idx >> 2, q = idx & 3;
        uint4 o;
        o.x = pack2(ld[q * 8 + 0][px], ld[q * 8 + 1][px]);
        o.y = pack2(ld[q * 8 + 2][px], ld[q * 8 + 3][px]);
        o.z = pack2(ld[q * 8 + 4][px], ld[q * 8 + 5][px]);
        o.w = pack2(ld[q * 8 + 6][px], ld[q * 8 + 7][px]);
        op[idx] = o;
    }
}

// ----------------------------------------------------------- MFMA conv ----
// Input: bf16 channel-last [n][zyx][CI]. Per block: (n,z,yt,xt) -> 64co x 16y x 16x.
// T14 async-stage: global loads -> regs issued BEFORE compute, ds_write after.
template <int CI, bool OUT_CL>
__global__ __launch_bounds__(256, 2) void conv5_mfma(const unsigned short* __restrict__ xin,
                                                     const unsigned short* __restrict__ wbuf,
                                                     void* __restrict__ outp,
                                                     float* __restrict__ part) {
    constexpr int NCH = CI / 32;
    constexpr int NS  = 5 * NCH;
    __shared__ __align__(16) unsigned short lds[2][12800];

    const int b   = blockIdx.x;
    const int xt  = b & 3;
    const int yt  = (b >> 2) & 3;
    const int z   = (b >> 4) & 63;
    const int n   = b >> 10;
    const int tid = threadIdx.x;
    const int lane = tid & 63, w = tid >> 6;
    const int xl = lane & 15, kh = lane >> 4;

    f32x4 acc[4][4];
#pragma unroll
    for (int pt = 0; pt < 4; ++pt)
#pragma unroll
        for (int c = 0; c < 4; ++c)
#pragma unroll
            for (int j = 0; j < 4; ++j) acc[pt][c][j] = 0.f;

    // precomputed per-thread staging geometry (same for every stage)
    const int khs = tid & 3;
    // r-th item: idx = tid + r*256 -> p = idx>>2, fixed khs
    uint4 rg[7];

    auto stage_load = [&](int s) {
        int dz = s / NCH, cich = s % NCH;
        int zi = z + dz - 2;
        bool zok = (unsigned)zi < 64u;
#pragma unroll
        for (int r = 0; r < 7; ++r) {
            int idx = tid + r * 256;
            uint4 v = make_uint4(0u, 0u, 0u, 0u);
            if (idx < 1600) {
                int p  = idx >> 2;
                int xx = p % 20, yy = p / 20;
                int yi = yt * 16 - 2 + yy;
                int xi = xt * 16 - 2 + xx;
                bool ok = zok && (unsigned)yi < 64u && (unsigned)xi < 64u;
                if (ok)
                    v = *(const uint4*)(xin
                        + ((size_t)(n * SP + zi * 4096 + yi * 64 + xi) * CI
                           + cich * 32 + khs * 8));
            }
            rg[r] = v;
        }
    };

    auto stage_write = [&](unsigned short* dst) {
#pragma unroll
        for (int r = 0; r < 7; ++r) {
            int idx = tid + r * 256;
            if (idx < 1600) {
                int p  = idx >> 2;
                int xx = p % 20, yy = p / 20;
                unsigned int off = ((unsigned)(yy * 20 + xx) * 64 + (unsigned)khs * 16)
                                   ^ ((unsigned)(xx & 3) << 4);
                *(uint4*)((char*)dst + off) = rg[r];
            }
        }
    };

    auto compute = [&](int s, const unsigned short* src) {
        int dz = s / NCH, cich = s % NCH;
        const unsigned short* wp = wbuf
            + ((size_t)((n * 5 + dz) * NCH + cich) * 25) * 2048
            + (size_t)xl * 32 + kh * 8;
#pragma unroll 1
        for (int dx = 0; dx < 5; ++dx) {
            int xx = xl + dx;
            s16x8 fr[8];
#pragma unroll
            for (int r = 0; r < 8; ++r) {
                int yy = w * 4 + r;
                unsigned int off = ((unsigned)(yy * 20 + xx) * 64 + (unsigned)kh * 16)
                                   ^ ((unsigned)(xx & 3) << 4);
                fr[r] = *(const s16x8*)((const char*)src + off);
            }
#pragma unroll
            for (int dy = 0; dy < 5; ++dy) {
                int t = dy * 5 + dx;
                s16x8 a[4];
#pragma unroll
                for (int c = 0; c < 4; ++c)
                    a[c] = *(const s16x8*)(wp + (size_t)t * 2048 + c * 512);
#pragma unroll
                for (int pt = 0; pt < 4; ++pt)
#pragma unroll
                    for (int c = 0; c < 4; ++c)
                        acc[pt][c] = __builtin_amdgcn_mfma_f32_16x16x32_bf16(
                            a[c], fr[pt + dy], acc[pt][c], 0, 0, 0);
            }
        }
    };

    stage_load(0);
    stage_write(lds[0]);
    __syncthreads();
#pragma unroll 1
    for (int s = 0; s < NS; ++s) {
        if (s + 1 < NS) stage_load(s + 1);     // issue early (async)
        __builtin_amdgcn_sched_barrier(0);     // keep loads above compute
        compute(s, lds[s & 1]);
        __builtin_amdgcn_sched_barrier(0);     // keep ds_writes below compute
        if (s + 1 < NS) stage_write(lds[(s + 1) & 1]);
        __syncthreads();
    }

    // ---- fused instance-norm partial sums (per block, per co) ----
    {
        float s1v[4][4], s2v[4][4];
#pragma unroll
        for (int c = 0; c < 4; ++c)
#pragma unroll
            for (int j = 0; j < 4; ++j) {
                float a0 = acc[0][c][j], a1 = acc[1][c][j],
                      a2 = acc[2][c][j], a3 = acc[3][c][j];
                s1v[c][j] = (a0 + a1) + (a2 + a3);
                s2v[c][j] = (a0 * a0 + a1 * a1) + (a2 * a2 + a3 * a3);
            }
#pragma unroll
        for (int o = 1; o < 16; o <<= 1) {
#pragma unroll
            for (int c = 0; c < 4; ++c)
#pragma unroll
                for (int j = 0; j < 4; ++j) {
                    s1v[c][j] += __shfl_xor(s1v[c][j], o, 64);
                    s2v[c][j] += __shfl_xor(s2v[c][j], o, 64);
                }
        }
        float* sh1 = (float*)&lds[1][0];      // [4][64]
        float* sh2 = sh1 + 256;
        if (xl == 0) {
#pragma unroll
            for (int c = 0; c < 4; ++c)
#pragma unroll
                for (int j = 0; j < 4; ++j) {
                    sh1[w * 64 + c * 16 + kh * 4 + j] = s1v[c][j];
                    sh2[w * 64 + c * 16 + kh * 4 + j] = s2v[c][j];
                }
        }
        __syncthreads();
        if (tid < 64) {
            float a = sh1[tid] + sh1[64 + tid] + sh1[128 + tid] + sh1[192 + tid];
            float q = sh2[tid] + sh2[64 + tid] + sh2[128 + tid] + sh2[192 + tid];
            part[(size_t)b * 128 + tid]      = a;
            part[(size_t)b * 128 + 64 + tid] = q;
        }
    }

    if (OUT_CL) {
        float* fl = (float*)&lds[0][0];       // 64 x 65 f32
#pragma unroll 1
        for (int pt = 0; pt < 4; ++pt) {
#pragma unroll
            for (int c = 0; c < 4; ++c)
#pragma unroll
                for (int j = 0; j < 4; ++j)
                    fl[(c * 16 + kh * 4 + j) * 65 + w * 16 + xl] = acc[pt][c][j];
            __syncthreads();
            int px = tid >> 2, cq = tid & 3;
            int y = yt * 16 + (px >> 4) * 4 + pt;
            int x = xt * 16 + (px & 15);
            unsigned short* op = (unsigned short*)outp
                + ((size_t)(n * SP + z * 4096 + y * 64 + x) * 64 + cq * 16);
            unsigned int tmp[8];
#pragma unroll
            for (int q = 0; q < 8; ++q)
                tmp[q] = pack2(fl[(cq * 16 + 2 * q) * 65 + px],
                               fl[(cq * 16 + 2 * q + 1) * 65 + px]);
            *(uint4*)op       = make_uint4(tmp[0], tmp[1], tmp[2], tmp[3]);
            *(uint4*)(op + 8) = make_uint4(tmp[4], tmp[5], tmp[6], tmp[7]);
            __syncthreads();
        }
    } else {
        float* op = (float*)outp;
#pragma unroll
        for (int pt = 0; pt < 4; ++pt) {
            int y = yt * 16 + w * 4 + pt;
#pragma unroll
            for (int c = 0; c < 4; ++c)
#pragma unroll
                for (int j = 0; j < 4; ++j)
                    op[((size_t)(n * 64 + c * 16 + kh * 4 + j) * 64 + z) * 4096
                       + y * 64 + xt * 16 + xl] = acc[pt][c][j];
        }
    }
}

// ------------------------------------------------- stats finalize ---------
__global__ void stats_fin_conv(const float* __restrict__ part, float* __restrict__ st) {
    int n = blockIdx.x;
    int t = threadIdx.x;
    int co = t & 63, q = t >> 6;
    float s1 = 0.f, s2 = 0.f;
    for (int bb = q * 256; bb < q * 256 + 256; ++bb) {
        const float* p = part + (size_t)(n * 1024 + bb) * 128;
        s1 += p[co];
        s2 += p[64 + co];
    }
    __shared__ float sh1[4][64], sh2[4][64];
    sh1[q][co] = s1; sh2[q][co] = s2;
    __syncthreads();
    if (t < 64) {
        float a = sh1[0][t] + sh1[1][t] + sh1[2][t] + sh1[3][t];
        float b = sh2[0][t] + sh2[1][t] + sh2[2][t] + sh2[3][t];
        float mean = a * (1.f / SP);
        float var  = b * (1.f / SP) - mean * mean;
        st[(n * 64 + t) * 2]     = mean;
        st[(n * 64 + t) * 2 + 1] = rsqrtf(var + 1e-5f);
    }
}

// -------------------------------------- norm+mish in-place, channel-last --
__global__ void norm_mish_cl_kernel(unsigned short* __restrict__ h,
                                    const float* __restrict__ st,
                                    const float* __restrict__ gamma,
                                    const float* __restrict__ beta) {
    size_t idx = (size_t)blockIdx.x * 256 + threadIdx.x;   // NB*SP*8 items
    uint4 v = ((uint4*)h)[idx];
    int c0 = ((int)(idx & 7)) * 8;
    size_t pix = idx >> 3;
    int n = (int)(pix >> 18);
    unsigned int* pv = &v.x;
#pragma unroll
    for (int q = 0; q < 4; ++q) {
        unsigned int wv = pv[q];
        unsigned int out = 0;
#pragma unroll
        for (int hv = 0; hv < 2; ++hv) {
            int c = c0 + 2 * q + hv;
            int nc = n * 64 + c;
            float val = bf2f((unsigned short)((wv >> (16 * hv)) & 0xffffu));
            float xh = (val - st[nc * 2]) * st[nc * 2 + 1] * gamma[c] + beta[c];
            out |= ((unsigned int)f2bf(mish_f(xh))) << (16 * hv);
        }
        pv[q] = out;
    }
    ((uint4*)h)[idx] = v;
}

// --------------------------------------------------------------- stats ----
__global__ void stats_kernel(const float* __restrict__ in, float* __restrict__ stats, int S) {
    int nc = blockIdx.x;
    const float4* p = reinterpret_cast<const float4*>(in + (size_t)nc * S);
    float s = 0.f, s2 = 0.f;
    int S4 = S >> 2;
    for (int i = threadIdx.x; i < S4; i += 256) {
        float4 v = p[i];
        s  += v.x + v.y + v.z + v.w;
        s2 += v.x * v.x + v.y * v.y + v.z * v.z + v.w * v.w;
    }
    __shared__ float sh[256], sh2[256];
    sh[threadIdx.x] = s; sh2[threadIdx.x] = s2;
    __syncthreads();
    for (int o = 128; o > 0; o >>= 1) {
        if (threadIdx.x < o) {
            sh[threadIdx.x]  += sh[threadIdx.x + o];
            sh2[threadIdx.x] += sh2[threadIdx.x + o];
        }
        __syncthreads();
    }
    if (threadIdx.x == 0) {
        float mean = sh[0] / S;
        float var  = sh2[0] / S - mean * mean;
        stats[nc * 2]     = mean;
        stats[nc * 2 + 1] = rsqrtf(var + 1e-5f);
    }
}

// ----------------------------------------------------------- norm+mish ----
template <int SHIFT>
__global__ void norm_mish_kernel(float* __restrict__ buf, const float* __restrict__ stats,
                                 const float* __restrict__ gamma, const float* __restrict__ beta,
                                 int total4) {
    int idx = blockIdx.x * 256 + threadIdx.x;
    if (idx >= total4) return;
    float4 v = reinterpret_cast<float4*>(buf)[idx];
    int nc = idx >> (SHIFT - 2);
    int c  = nc & 63;
    float mean = stats[nc * 2], inv = stats[nc * 2 + 1];
    float ga = gamma[c], be = beta[c];
    float* pv = &v.x;
#pragma unroll
    for (int k = 0; k < 4; ++k) {
        float xh = (pv[k] - mean) * inv * ga + be;
        pv[k] = mish_f(xh);
    }
    reinterpret_cast<float4*>(buf)[idx] = v;
}

// ----------------------------------------------------------- down conv ----
__global__ __launch_bounds__(256) void down_conv_kernel(const float* __restrict__ xin,
                                                        const float* __restrict__ dw,
                                                        float* __restrict__ out) {
    __shared__ float ls[8][2][8][64];
    int b   = blockIdx.x;
    int yt  = b & 7;
    int z   = (b >> 3) & 31;
    int n   = b >> 8;
    int tid = threadIdx.x;
    int xo  = tid & 31;
    int cog = tid >> 5;

    float acc[4][8];
#pragma unroll
    for (int yo = 0; yo < 4; ++yo)
#pragma unroll
        for (int j = 0; j < 8; ++j) acc[yo][j] = 0.f;

    for (int cc = 0; cc < 8; ++cc) {
        for (int idx = tid; idx < 8192; idx += 256) {
            int xx = idx & 63;
            int yy = (idx >> 6) & 7;
            int dz = (idx >> 9) & 1;
            int c  = idx >> 10;
            ls[c][dz][yy][xx] = xin[((size_t)(n * CO + cc * 8 + c) * 64 + 2 * z + dz) * 4096
                                    + (yt * 8 + yy) * 64 + xx];
        }
        __syncthreads();
#pragma unroll 1
        for (int c = 0; c < 8; ++c) {
            int ci = cc * 8 + c;
#pragma unroll
            for (int tap = 0; tap < 8; ++tap) {
                int dz = tap >> 2, dy = (tap >> 1) & 1, dx = tap & 1;
                float w[8];
#pragma unroll
                for (int j = 0; j < 8; ++j)
                    w[j] = dw[((size_t)(cog * 8 + j) * CO + ci) * 8 + tap];
#pragma unroll
                for (int yo = 0; yo < 4; ++yo) {
                    float xv = ls[c][dz][yo * 2 + dy][2 * xo + dx];
#pragma unroll
                    for (int j = 0; j < 8; ++j) acc[yo][j] += w[j] * xv;
                }
            }
        }
        __syncthreads();
    }
#pragma unroll
    for (int yo = 0; yo < 4; ++yo)
#pragma unroll
        for (int j = 0; j < 8; ++j)
            out[((size_t)(n * CO + cog * 8 + j) * 32 + z) * 1024 + (yt * 4 + yo) * 32 + xo]
                = acc[yo][j];
}

// -------------------------------------------------------------- launch ----
extern "C" void kernel_launch(void* const* d_in, const int* in_sizes, int n_in,
                              void* d_out, int out_size, void* d_ws, size_t ws_size,
                              hipStream_t stream) {
    const float* x      = (const float*)d_in[0];
    const float* t      = (const float*)d_in[1];
    const float* l1_c5  = (const float*)d_in[2];
    const float* l1_c3  = (const float*)d_in[3];
    const float* l1_c1  = (const float*)d_in[4];
    const float* l1_a3  = (const float*)d_in[5];
    const float* l1_a5  = (const float*)d_in[6];
    const float* l1_gw  = (const float*)d_in[7];
    const float* l1_gb  = (const float*)d_in[8];
    const float* l1_ga  = (const float*)d_in[9];
    const float* l1_be  = (const float*)d_in[10];
    const float* l2_c5  = (const float*)d_in[11];
    const float* l2_c3  = (const float*)d_in[12];
    const float* l2_c1  = (const float*)d_in[13];
    const float* l2_a3  = (const float*)d_in[14];
    const float* l2_a5  = (const float*)d_in[15];
    const float* l2_gw  = (const float*)d_in[16];
    const float* l2_gb  = (const float*)d_in[17];
    const float* l2_ga  = (const float*)d_in[18];
    const float* l2_be  = (const float*)d_in[19];
    const float* down_w = (const float*)d_in[20];
    const float* dn_ga  = (const float*)d_in[21];
    const float* dn_be  = (const float*)d_in[22];

    char* ws = (char*)d_ws;
    unsigned short* xcl = (unsigned short*)(ws);                  // 33,554,432 B
    unsigned short* h2  = (unsigned short*)(ws + 33554432);       // 67,108,864 B
    unsigned short* w1  = (unsigned short*)(ws + 100663296);      //  1,024,000 B
    unsigned short* w2  = (unsigned short*)(ws + 101687296);      //  2,048,000 B
    float* g1    = (float*)(ws + 103735296);
    float* g2    = (float*)(ws + 103737856);
    float* st1   = (float*)(ws + 103740416);
    float* st2   = (float*)(ws + 103741440);
    float* st3   = (float*)(ws + 103742464);
    float* part1 = (float*)(ws + 103743488);                      //  1,048,576 B
    float* part2 = (float*)(ws + 104792064);                      //  1,048,576 B

    float* yout  = (float*)d_out;
    float* xskip = (float*)d_out + Y_SZ;

    gate_kernel<<<1, 128, 0, stream>>>(t, l1_gw, l1_gb, g1);
    gate_kernel<<<1, 128, 0, stream>>>(t, l2_gw, l2_gb, g2);
    synth_kernel<32><<<(NB * CO * 32 * 125 + 255) / 256, 256, 0, stream>>>(
        g1, l1_c5, l1_c3, l1_c1, l1_a3, l1_a5, w1);
    synth_kernel<64><<<(NB * CO * 64 * 125 + 255) / 256, 256, 0, stream>>>(
        g2, l2_c5, l2_c3, l2_c1, l2_a3, l2_a5, w2);
    x_to_cl<<<2048, 256, 0, stream>>>(x, xcl);

    // layer 1
    conv5_mfma<32, true><<<2048, 256, 0, stream>>>(xcl, w1, h2, part1);
    stats_fin_conv<<<2, 256, 0, stream>>>(part1, st1);
    norm_mish_cl_kernel<<<16384, 256, 0, stream>>>(h2, st1, l1_ga, l1_be);

    // layer 2
    conv5_mfma<64, false><<<2048, 256, 0, stream>>>(h2, w2, xskip, part2);
    stats_fin_conv<<<2, 256, 0, stream>>>(part2, st2);
    norm_mish_kernel<18><<<(NC * SP / 4 + 255) / 256, 256, 0, stream>>>(
        xskip, st2, l2_ga, l2_be, NC * SP / 4);

    // downsample
    down_conv_kernel<<<NB * 32 * 8, 256, 0, stream>>>(xskip, down_w, yout);
    stats_kernel<<<NC, 256, 0, stream>>>(yout, st3, 32768);
    norm_mish_kernel<15><<<(NC * 32768 / 4 + 255) / 256, 256, 0, stream>>>(
        yout, st3, dn_ga, dn_be, NC * 32768 / 4);
}

// Round 5
// 1085.079 us; speedup vs baseline: 12.2293x; 1.0475x over previous
//
#include <hip/hip_runtime.h>
#include <cstdint>
#include <cstddef>

constexpr int NB  = 2;
constexpr int CO  = 64;
constexpr int DIM = 64;
constexpr int SP  = DIM * DIM * DIM;       // 262144
constexpr int NC  = NB * CO;               // 128
constexpr int Y_SZ = NB * CO * 32 * 32 * 32;

typedef float f32x4 __attribute__((ext_vector_type(4)));
typedef short s16x8 __attribute__((ext_vector_type(8)));

__device__ __forceinline__ unsigned short f2bf(float f) {
    unsigned int u = __float_as_uint(f);
    unsigned int r = (u + 0x7fffu + ((u >> 16) & 1u)) >> 16;
    return (unsigned short)r;
}
__device__ __forceinline__ float bf2f(unsigned short u) {
    return __uint_as_float((unsigned int)u << 16);
}
__device__ __forceinline__ unsigned int pack2(float a, float b) {
    return (unsigned int)f2bf(a) | ((unsigned int)f2bf(b) << 16);
}
// mish(x) = x * tanh(softplus(x)) = x*(e^2+2e)/(e^2+2e+2), e = exp(x)
__device__ __forceinline__ float mish_f(float x) {
    float e = __expf(x);
    float num = e * (e + 2.f);
    float r = x * num * __builtin_amdgcn_rcpf(num + 2.f);
    return (x > 15.f) ? x : r;
}

__device__ __forceinline__ void gload_lds16(const void* g, void* l) {
    __builtin_amdgcn_global_load_lds(
        (const __attribute__((address_space(1))) unsigned int*)g,
        (__attribute__((address_space(3))) unsigned int*)l, 16, 0, 0);
}

// ---------------------------------------------------------------- zero ----
__global__ void zero_kernel(float* __restrict__ z) { z[threadIdx.x] = 0.f; }

// ---------------------------------------------------------------- gate ----
__global__ void gate_kernel(const float* __restrict__ t, const float* __restrict__ gw,
                            const float* __restrict__ gb, float* __restrict__ g) {
    int tid = threadIdx.x;
    if (tid >= NB * CO) return;
    int n = tid >> 6, co = tid & 63;
    float tl[10];
#pragma unroll
    for (int k = 0; k < 10; ++k) tl[k] = t[n * 10 + k];
    float l[5];
#pragma unroll
    for (int e = 0; e < 5; ++e) {
        int row = e * CO + co;
        float acc = gb[row];
#pragma unroll
        for (int k = 0; k < 10; ++k) acc += tl[k] * gw[row * 10 + k];
        l[e] = acc;
    }
    float m = l[0];
#pragma unroll
    for (int e = 1; e < 5; ++e) m = fmaxf(m, l[e]);
    float s = 0.f;
#pragma unroll
    for (int e = 0; e < 5; ++e) { l[e] = expf(l[e] - m); s += l[e]; }
    float inv = 1.f / s;
#pragma unroll
    for (int e = 0; e < 5; ++e) g[(n * 5 + e) * CO + co] = l[e] * inv;
}

// --------------------------------------------------------------- synth ----
// wbuf (bf16): [n][dz(5)][cich(CI/32)][t(25)][co(64)][cil(32)]
template <int CI>
__global__ void synth_kernel(const float* __restrict__ g,
                             const float* __restrict__ c5, const float* __restrict__ c3,
                             const float* __restrict__ c1, const float* __restrict__ a3,
                             const float* __restrict__ a5, unsigned short* __restrict__ wbuf) {
    int idx = blockIdx.x * 256 + threadIdx.x;
    constexpr int TOTAL = NB * CO * CI * 125;
    if (idx >= TOTAL) return;
    int tap = idx % 125;
    int ci  = (idx / 125) % CI;
    int co  = (idx / (125 * CI)) % CO;
    int n   = idx / (125 * CI * CO);
    const float* gn = g + n * 5 * CO;
    float g0 = gn[0 * CO + co], g1 = gn[1 * CO + co], g2 = gn[2 * CO + co],
          g3 = gn[3 * CO + co], g4 = gn[4 * CO + co];
    int dz = tap / 25, dy = (tap / 5) % 5, dx = tap % 5;
    int oc = co * CI + ci;
    float v = g0 * c5[(size_t)oc * 125 + tap] + g4 * a5[oc] * (1.f / 125.f);
    if (dz >= 1 && dz <= 3 && dy >= 1 && dy <= 3 && dx >= 1 && dx <= 3)
        v += g1 * c3[(size_t)oc * 27 + (dz - 1) * 9 + (dy - 1) * 3 + (dx - 1)]
           + g3 * a3[oc] * (1.f / 27.f);
    if (dz == 2 && dy == 2 && dx == 2) v += g2 * c1[oc];
    int t = (dy * 5 + dx);
    int cich = ci >> 5, cil = ci & 31;
    wbuf[((((size_t)(n * 5 + dz) * (CI / 32) + cich) * 25 + t) * 64 + co) * 32 + cil] = f2bf(v);
}

// -------------------------------------------------------------- x->CL -----
// f32 NCDHW (n,32,zyx) -> bf16 channel-last [n][zyx][32]
__global__ __launch_bounds__(256) void x_to_cl(const float* __restrict__ x,
                                               unsigned short* __restrict__ xcl) {
    __shared__ float ld[32][256];
    int b = blockIdx.x;                   // 2048 = n(2) x 1024
    int n = b >> 10;
    size_t base = (size_t)(b & 1023) * 256;
    int tid = threadIdx.x;
    const float* xp = x + (size_t)n * 32 * SP + base + tid;
#pragma unroll
    for (int c = 0; c < 32; ++c) ld[c][tid] = xp[(size_t)c * SP];
    __syncthreads();
    uint4* op = (uint4*)(xcl + ((size_t)n * SP + base) * 32);
#pragma unroll
    for (int r = 0; r < 4; ++r) {
        int idx = r * 256 + tid;
        int px = idx >> 2, q = idx & 3;
        uint4 o;
        o.x = pack2(ld[q * 8 + 0][px], ld[q * 8 + 1][px]);
        o.y = pack2(ld[q * 8 + 2][px], ld[q * 8 + 3][px]);
        o.z = pack2(ld[q * 8 + 4][px], ld[q * 8 + 5][px]);
        o.w = pack2(ld[q * 8 + 6][px], ld[q * 8 + 7][px]);
        op[idx] = o;
    }
}

// ----------------------------------------------------------- MFMA conv ----
// Input bf16 channel-last [n][zyx][CI]. Block (512 thr): (n,z,yt,xt) ->
// 64co x 16y x 16x. Wave (yh, cq): 8 y-rows x 16 co. Staging via
// global_load_lds (linear LDS, no swizzle). Fused IN partial sums -> part.
template <int CI, bool OUT_CL>
__global__ __launch_bounds__(512, 4) void conv5_mfma(const unsigned short* __restrict__ xin,
                                                     const unsigned short* __restrict__ wbuf,
                                                     void* __restrict__ outp,
                                                     float* __restrict__ part,
                                                     const void* __restrict__ zbuf) {
    constexpr int NCH = CI / 32;
    constexpr int NS  = 5 * NCH;
    __shared__ __align__(16) unsigned short lds[2][12800];   // 2 x 25.6 KB

    const int b   = blockIdx.x;
    const int xt  = b & 3;
    const int yt  = (b >> 2) & 3;
    const int z   = (b >> 4) & 63;
    const int n   = b >> 10;
    const int tid = threadIdx.x;
    const int lane = tid & 63, wv = tid >> 6;
    const int xl = lane & 15, kh = lane >> 4;
    const int yh = wv >> 2, cq = wv & 3;

    f32x4 acc[8];
#pragma unroll
    for (int pt = 0; pt < 8; ++pt)
#pragma unroll
        for (int j = 0; j < 4; ++j) acc[pt][j] = 0.f;

    // staging geometry: item idx = tid + r*512 (< 1600); linear LDS dest.
    long goff[4]; int gval[4];
#pragma unroll
    for (int r = 0; r < 4; ++r) {
        int idx = tid + r * 512;
        int p = idx >> 2, khs = idx & 3;
        int xx = p % 20, yy = p / 20;
        int yi = yt * 16 - 2 + yy, xi = xt * 16 - 2 + xx;
        gval[r] = ((unsigned)yi < 64u) && ((unsigned)xi < 64u);
        goff[r] = ((long)(yi * 64 + xi) * CI + khs * 8) * 2;
    }

    auto stage = [&](int s, int buf) {
        int dz = s / NCH, cich = s % NCH;
        int zi = z + dz - 2;
        bool zok = (unsigned)zi < 64u;
        const char* pb = (const char*)xin
                       + ((size_t)(n * SP + zi * 4096) * CI + cich * 32) * 2;
        char* lb = (char*)&lds[buf][0];
#pragma unroll
        for (int r = 0; r < 4; ++r) {
            int idx = tid + r * 512;
            if (idx < 1600) {
                const void* g = (zok && gval[r]) ? (const void*)(pb + goff[r]) : zbuf;
                gload_lds16(g, lb + idx * 16);
            }
        }
    };

    auto compute = [&](int s, int buf) {
        int dz = s / NCH, cich = s % NCH;
        const unsigned short* wp = wbuf
            + ((size_t)((n * 5 + dz) * NCH + cich) * 25) * 2048
            + cq * 512 + xl * 32 + kh * 8;
        const char* src = (const char*)&lds[buf][0];
        __builtin_amdgcn_s_setprio(1);
#pragma unroll 1
        for (int dx = 0; dx < 5; ++dx) {
            int xx = xl + dx;
            s16x8 fr[12];
#pragma unroll
            for (int r = 0; r < 12; ++r) {
                int row = yh * 8 + r;
                fr[r] = *(const s16x8*)(src + (size_t)(row * 20 + xx) * 64 + kh * 16);
            }
#pragma unroll
            for (int dy = 0; dy < 5; ++dy) {
                s16x8 a = *(const s16x8*)(wp + (size_t)(dy * 5 + dx) * 2048);
#pragma unroll
                for (int pt = 0; pt < 8; ++pt)
                    acc[pt] = __builtin_amdgcn_mfma_f32_16x16x32_bf16(
                        a, fr[pt + dy], acc[pt], 0, 0, 0);
            }
        }
        __builtin_amdgcn_s_setprio(0);
    };

    stage(0, 0);
    __syncthreads();
#pragma unroll 1
    for (int s = 0; s < NS; ++s) {
        if (s + 1 < NS) stage(s + 1, (s + 1) & 1);
        compute(s, s & 1);
        __syncthreads();
    }

    // ---- fused instance-norm partial sums ----
    {
        float s1[4], s2[4];
#pragma unroll
        for (int j = 0; j < 4; ++j) { s1[j] = 0.f; s2[j] = 0.f; }
#pragma unroll
        for (int pt = 0; pt < 8; ++pt)
#pragma unroll
            for (int j = 0; j < 4; ++j) {
                float v = acc[pt][j];
                s1[j] += v; s2[j] += v * v;
            }
#pragma unroll
        for (int o = 1; o < 16; o <<= 1)
#pragma unroll
            for (int j = 0; j < 4; ++j) {
                s1[j] += __shfl_xor(s1[j], o, 64);
                s2[j] += __shfl_xor(s2[j], o, 64);
            }
        if (xl == 0) {
            int co = cq * 16 + kh * 4;
            float* pp = part + ((size_t)b * 2 + yh) * 128;
#pragma unroll
            for (int j = 0; j < 4; ++j) {
                pp[co + j]      = s1[j];
                pp[64 + co + j] = s2[j];
            }
        }
    }

    if (OUT_CL) {
#pragma unroll
        for (int pt = 0; pt < 8; ++pt) {
            int y = yt * 16 + yh * 8 + pt;
            unsigned short* op = (unsigned short*)outp
                + ((size_t)(n * SP + z * 4096 + y * 64 + xt * 16 + xl)) * 64
                + cq * 16 + kh * 4;
            uint2 o;
            o.x = pack2(acc[pt][0], acc[pt][1]);
            o.y = pack2(acc[pt][2], acc[pt][3]);
            *(uint2*)op = o;
        }
    } else {
        float* op = (float*)outp;
#pragma unroll
        for (int pt = 0; pt < 8; ++pt) {
            int y = yt * 16 + yh * 8 + pt;
#pragma unroll
            for (int j = 0; j < 4; ++j)
                op[((size_t)(n * 64 + cq * 16 + kh * 4 + j) * 64 + z) * 4096
                   + y * 64 + xt * 16 + xl] = acc[pt][j];
        }
    }
}

// ------------------------------------------------- stats finalize (conv) --
// part: per n, 2048 chunks of 128 floats (64 sum + 64 sumsq). grid = 2.
__global__ void stats_fin_conv(const float* __restrict__ part, float* __restrict__ st) {
    int n = blockIdx.x;
    int t = threadIdx.x;
    int co = t & 63, q = t >> 6;
    float s1 = 0.f, s2 = 0.f;
    for (int c = q; c < 2048; c += 4) {
        const float* p = part + ((size_t)n * 2048 + c) * 128;
        s1 += p[co];
        s2 += p[64 + co];
    }
    __shared__ float sh1[4][64], sh2[4][64];
    sh1[q][co] = s1; sh2[q][co] = s2;
    __syncthreads();
    if (t < 64) {
        float a = sh1[0][t] + sh1[1][t] + sh1[2][t] + sh1[3][t];
        float b = sh2[0][t] + sh2[1][t] + sh2[2][t] + sh2[3][t];
        float mean = a * (1.f / SP);
        float var  = b * (1.f / SP) - mean * mean;
        st[(n * 64 + t) * 2]     = mean;
        st[(n * 64 + t) * 2 + 1] = rsqrtf(var + 1e-5f);
    }
}

// -------------------------------------- norm+mish in-place, channel-last --
__global__ void norm_mish_cl_kernel(unsigned short* __restrict__ h,
                                    const float* __restrict__ st,
                                    const float* __restrict__ gamma,
                                    const float* __restrict__ beta) {
    size_t idx = (size_t)blockIdx.x * 256 + threadIdx.x;   // NB*SP*8 items
    uint4 v = ((uint4*)h)[idx];
    int c0 = ((int)(idx & 7)) * 8;
    size_t pix = idx >> 3;
    int n = (int)(pix >> 18);
    unsigned int* pv = &v.x;
#pragma unroll
    for (int q = 0; q < 4; ++q) {
        unsigned int wv = pv[q];
        unsigned int out = 0;
#pragma unroll
        for (int hv = 0; hv < 2; ++hv) {
            int c = c0 + 2 * q + hv;
            int nc = n * 64 + c;
            float val = bf2f((unsigned short)((wv >> (16 * hv)) & 0xffffu));
            float xh = (val - st[nc * 2]) * st[nc * 2 + 1] * gamma[c] + beta[c];
            out |= ((unsigned int)f2bf(mish_f(xh))) << (16 * hv);
        }
        pv[q] = out;
    }
    ((uint4*)h)[idx] = v;
}

// ----------------------------------------------------------- norm+mish ----
template <int SHIFT>
__global__ void norm_mish_kernel(float* __restrict__ buf, const float* __restrict__ stats,
                                 const float* __restrict__ gamma, const float* __restrict__ beta,
                                 int total4) {
    int idx = blockIdx.x * 256 + threadIdx.x;
    if (idx >= total4) return;
    float4 v = reinterpret_cast<float4*>(buf)[idx];
    int nc = idx >> (SHIFT - 2);
    int c  = nc & 63;
    float mean = stats[nc * 2], inv = stats[nc * 2 + 1];
    float ga = gamma[c], be = beta[c];
    float* pv = &v.x;
#pragma unroll
    for (int k = 0; k < 4; ++k) {
        float xh = (pv[k] - mean) * inv * ga + be;
        pv[k] = mish_f(xh);
    }
    reinterpret_cast<float4*>(buf)[idx] = v;
}

// ----------------------------------------------------------- down conv ----
// Fused: reads RAW xskip, applies norm+mish (st2), writes normalized value
// back in place, does 2x2x2 stride-2 conv, writes raw y + y-stats partials.
__global__ __launch_bounds__(256) void down_conv_kernel(float* __restrict__ xin,
                                                        const float* __restrict__ dw,
                                                        const float* __restrict__ st,
                                                        const float* __restrict__ gamma,
                                                        const float* __restrict__ beta,
                                                        float* __restrict__ out,
                                                        float* __restrict__ part) {
    __shared__ float ls[8][2][8][64];
    int b   = blockIdx.x;
    int yt  = b & 7;
    int z   = (b >> 3) & 31;
    int n   = b >> 8;
    int tid = threadIdx.x;
    int xo  = tid & 31;
    int cog = tid >> 5;

    float acc[4][8];
#pragma unroll
    for (int yo = 0; yo < 4; ++yo)
#pragma unroll
        for (int j = 0; j < 8; ++j) acc[yo][j] = 0.f;

    for (int cc = 0; cc < 8; ++cc) {
        for (int idx = tid; idx < 8192; idx += 256) {
            int xx = idx & 63;
            int yy = (idx >> 6) & 7;
            int dz = (idx >> 9) & 1;
            int c  = idx >> 10;
            int ci = cc * 8 + c;
            size_t ga = ((size_t)(n * CO + ci) * 64 + 2 * z + dz) * 4096
                      + (yt * 8 + yy) * 64 + xx;
            float v = xin[ga];
            int nc = n * 64 + ci;
            float nv = mish_f((v - st[nc * 2]) * st[nc * 2 + 1] * gamma[ci] + beta[ci]);
            ls[c][dz][yy][xx] = nv;
            xin[ga] = nv;
        }
        __syncthreads();
#pragma unroll 1
        for (int c = 0; c < 8; ++c) {
            int ci = cc * 8 + c;
#pragma unroll
            for (int tap = 0; tap < 8; ++tap) {
                int dz = tap >> 2, dy = (tap >> 1) & 1, dx = tap & 1;
                float w[8];
#pragma unroll
                for (int j = 0; j < 8; ++j)
                    w[j] = dw[((size_t)(cog * 8 + j) * CO + ci) * 8 + tap];
#pragma unroll
                for (int yo = 0; yo < 4; ++yo) {
                    float xv = ls[c][dz][yo * 2 + dy][2 * xo + dx];
#pragma unroll
                    for (int j = 0; j < 8; ++j) acc[yo][j] += w[j] * xv;
                }
            }
        }
        __syncthreads();
    }
#pragma unroll
    for (int yo = 0; yo < 4; ++yo)
#pragma unroll
        for (int j = 0; j < 8; ++j)
            out[((size_t)(n * CO + cog * 8 + j) * 32 + z) * 1024 + (yt * 4 + yo) * 32 + xo]
                = acc[yo][j];

    // y-stats partials
    float s1[8], s2[8];
#pragma unroll
    for (int j = 0; j < 8; ++j) { s1[j] = 0.f; s2[j] = 0.f; }
#pragma unroll
    for (int yo = 0; yo < 4; ++yo)
#pragma unroll
        for (int j = 0; j < 8; ++j) {
            float v = acc[yo][j];
            s1[j] += v; s2[j] += v * v;
        }
#pragma unroll
    for (int o = 1; o < 32; o <<= 1)
#pragma unroll
        for (int j = 0; j < 8; ++j) {
            s1[j] += __shfl_xor(s1[j], o, 64);
            s2[j] += __shfl_xor(s2[j], o, 64);
        }
    if (xo == 0) {
        float* pp = part + (size_t)b * 128;
#pragma unroll
        for (int j = 0; j < 8; ++j) {
            pp[cog * 8 + j]      = s1[j];
            pp[64 + cog * 8 + j] = s2[j];
        }
    }
}

// ------------------------------------------------- stats finalize (down) --
__global__ void stats_fin_down(const float* __restrict__ part, float* __restrict__ st) {
    int n = blockIdx.x;
    int t = threadIdx.x;
    int co = t & 63, q = t >> 6;
    float s1 = 0.f, s2 = 0.f;
    for (int c = q; c < 256; c += 4) {
        const float* p = part + ((size_t)n * 256 + c) * 128;
        s1 += p[co];
        s2 += p[64 + co];
    }
    __shared__ float sh1[4][64], sh2[4][64];
    sh1[q][co] = s1; sh2[q][co] = s2;
    __syncthreads();
    if (t < 64) {
        float a = sh1[0][t] + sh1[1][t] + sh1[2][t] + sh1[3][t];
        float b = sh2[0][t] + sh2[1][t] + sh2[2][t] + sh2[3][t];
        float mean = a * (1.f / 32768.f);
        float var  = b * (1.f / 32768.f) - mean * mean;
        st[(n * 64 + t) * 2]     = mean;
        st[(n * 64 + t) * 2 + 1] = rsqrtf(var + 1e-5f);
    }
}

// -------------------------------------------------------------- launch ----
extern "C" void kernel_launch(void* const* d_in, const int* in_sizes, int n_in,
                              void* d_out, int out_size, void* d_ws, size_t ws_size,
                              hipStream_t stream) {
    const float* x      = (const float*)d_in[0];
    const float* t      = (const float*)d_in[1];
    const float* l1_c5  = (const float*)d_in[2];
    const float* l1_c3  = (const float*)d_in[3];
    const float* l1_c1  = (const float*)d_in[4];
    const float* l1_a3  = (const float*)d_in[5];
    const float* l1_a5  = (const float*)d_in[6];
    const float* l1_gw  = (const float*)d_in[7];
    const float* l1_gb  = (const float*)d_in[8];
    const float* l1_ga  = (const float*)d_in[9];
    const float* l1_be  = (const float*)d_in[10];
    const float* l2_c5  = (const float*)d_in[11];
    const float* l2_c3  = (const float*)d_in[12];
    const float* l2_c1  = (const float*)d_in[13];
    const float* l2_a3  = (const float*)d_in[14];
    const float* l2_a5  = (const float*)d_in[15];
    const float* l2_gw  = (const float*)d_in[16];
    const float* l2_gb  = (const float*)d_in[17];
    const float* l2_ga  = (const float*)d_in[18];
    const float* l2_be  = (const float*)d_in[19];
    const float* down_w = (const float*)d_in[20];
    const float* dn_ga  = (const float*)d_in[21];
    const float* dn_be  = (const float*)d_in[22];

    char* ws = (char*)d_ws;
    unsigned short* xcl = (unsigned short*)(ws);                  // 33,554,432 B
    unsigned short* h2  = (unsigned short*)(ws + 33554432);       // 67,108,864 B
    unsigned short* w1  = (unsigned short*)(ws + 100663296);      //  1,024,000 B
    unsigned short* w2  = (unsigned short*)(ws + 101687296);      //  2,048,000 B
    float* g1    = (float*)(ws + 103735296);
    float* g2    = (float*)(ws + 103737856);
    float* st1   = (float*)(ws + 103740416);
    float* st2   = (float*)(ws + 103741440);
    float* st3   = (float*)(ws + 103742464);
    float* part1 = (float*)(ws + 103743488);                      //  2,097,152 B
    float* part2 = (float*)(ws + 105840640);                      //  2,097,152 B
    float* part3 = (float*)(ws + 107937792);                      //    262,144 B
    float* zbuf  = (float*)(ws + 108199936);                      //        256 B

    float* yout  = (float*)d_out;
    float* xskip = (float*)d_out + Y_SZ;

    zero_kernel<<<1, 64, 0, stream>>>(zbuf);
    gate_kernel<<<1, 128, 0, stream>>>(t, l1_gw, l1_gb, g1);
    gate_kernel<<<1, 128, 0, stream>>>(t, l2_gw, l2_gb, g2);
    synth_kernel<32><<<(NB * CO * 32 * 125 + 255) / 256, 256, 0, stream>>>(
        g1, l1_c5, l1_c3, l1_c1, l1_a3, l1_a5, w1);
    synth_kernel<64><<<(NB * CO * 64 * 125 + 255) / 256, 256, 0, stream>>>(
        g2, l2_c5, l2_c3, l2_c1, l2_a3, l2_a5, w2);
    x_to_cl<<<2048, 256, 0, stream>>>(x, xcl);

    // layer 1: conv (bf16 CL in -> bf16 CL raw out) + fused stats partials
    conv5_mfma<32, true><<<2048, 512, 0, stream>>>(xcl, w1, h2, part1, zbuf);
    stats_fin_conv<<<2, 256, 0, stream>>>(part1, st1);
    norm_mish_cl_kernel<<<16384, 256, 0, stream>>>(h2, st1, l1_ga, l1_be);

    // layer 2: conv (bf16 CL in -> f32 NCDHW raw into x_skip) + partials
    conv5_mfma<64, false><<<2048, 512, 0, stream>>>(h2, w2, xskip, part2, zbuf);
    stats_fin_conv<<<2, 256, 0, stream>>>(part2, st2);

    // downsample: fused norm+mish(x_skip, in place) + conv + y-stats partials
    down_conv_kernel<<<NB * 32 * 8, 256, 0, stream>>>(xskip, down_w, st2, l2_ga, l2_be,
                                                      yout, part3);
    stats_fin_down<<<2, 256, 0, stream>>>(part3, st3);
    norm_mish_kernel<15><<<(NC * 32768 / 4 + 255) / 256, 256, 0, stream>>>(
        yout, st3, dn_ga, dn_be, NC * 32768 / 4);
}

// Round 6
// 871.166 us; speedup vs baseline: 15.2322x; 1.2455x over previous
//
#include <hip/hip_runtime.h>
#include <cstdint>
#include <cstddef>

constexpr int NB  = 2;
constexpr int CO  = 64;
constexpr int DIM = 64;
constexpr int SP  = DIM * DIM * DIM;       // 262144
constexpr int NC  = NB * CO;               // 128
constexpr int Y_SZ = NB * CO * 32 * 32 * 32;

typedef float f32x4 __attribute__((ext_vector_type(4)));
typedef short s16x8 __attribute__((ext_vector_type(8)));

__device__ __forceinline__ unsigned short f2bf(float f) {
    unsigned int u = __float_as_uint(f);
    unsigned int r = (u + 0x7fffu + ((u >> 16) & 1u)) >> 16;
    return (unsigned short)r;
}
__device__ __forceinline__ float bf2f(unsigned short u) {
    return __uint_as_float((unsigned int)u << 16);
}
__device__ __forceinline__ unsigned int pack2(float a, float b) {
    return (unsigned int)f2bf(a) | ((unsigned int)f2bf(b) << 16);
}
// mish(x) = x * tanh(softplus(x)) = x*(e^2+2e)/(e^2+2e+2), e = exp(x)
__device__ __forceinline__ float mish_f(float x) {
    float e = __expf(x);
    float num = e * (e + 2.f);
    float r = x * num * __builtin_amdgcn_rcpf(num + 2.f);
    return (x > 15.f) ? x : r;
}

__device__ __forceinline__ void gload_lds16(const void* g, void* l) {
    __builtin_amdgcn_global_load_lds(
        (const __attribute__((address_space(1))) unsigned int*)g,
        (__attribute__((address_space(3))) unsigned int*)l, 16, 0, 0);
}

// -------------------------------------------------------- gate (+zero) ----
__global__ void gate_kernel(const float* __restrict__ t, const float* __restrict__ gw,
                            const float* __restrict__ gb, float* __restrict__ g,
                            float* __restrict__ zbuf) {
    int tid = threadIdx.x;
    if (tid >= 128) { if (tid < 192) zbuf[tid - 128] = 0.f; return; }
    int n = tid >> 6, co = tid & 63;
    float tl[10];
#pragma unroll
    for (int k = 0; k < 10; ++k) tl[k] = t[n * 10 + k];
    float l[5];
#pragma unroll
    for (int e = 0; e < 5; ++e) {
        int row = e * CO + co;
        float acc = gb[row];
#pragma unroll
        for (int k = 0; k < 10; ++k) acc += tl[k] * gw[row * 10 + k];
        l[e] = acc;
    }
    float m = l[0];
#pragma unroll
    for (int e = 1; e < 5; ++e) m = fmaxf(m, l[e]);
    float s = 0.f;
#pragma unroll
    for (int e = 0; e < 5; ++e) { l[e] = expf(l[e] - m); s += l[e]; }
    float inv = 1.f / s;
#pragma unroll
    for (int e = 0; e < 5; ++e) g[(n * 5 + e) * CO + co] = l[e] * inv;
}

// --------------------------------------------------------------- synth ----
// wbuf (bf16): [n][dz(5)][cich(CI/32)][t(25)][co(64)][cil(32)]
template <int CI>
__global__ void synth_kernel(const float* __restrict__ g,
                             const float* __restrict__ c5, const float* __restrict__ c3,
                             const float* __restrict__ c1, const float* __restrict__ a3,
                             const float* __restrict__ a5, unsigned short* __restrict__ wbuf) {
    int idx = blockIdx.x * 256 + threadIdx.x;
    constexpr int TOTAL = NB * CO * CI * 125;
    if (idx >= TOTAL) return;
    int tap = idx % 125;
    int ci  = (idx / 125) % CI;
    int co  = (idx / (125 * CI)) % CO;
    int n   = idx / (125 * CI * CO);
    const float* gn = g + n * 5 * CO;
    float g0 = gn[0 * CO + co], g1 = gn[1 * CO + co], g2 = gn[2 * CO + co],
          g3 = gn[3 * CO + co], g4 = gn[4 * CO + co];
    int dz = tap / 25, dy = (tap / 5) % 5, dx = tap % 5;
    int oc = co * CI + ci;
    float v = g0 * c5[(size_t)oc * 125 + tap] + g4 * a5[oc] * (1.f / 125.f);
    if (dz >= 1 && dz <= 3 && dy >= 1 && dy <= 3 && dx >= 1 && dx <= 3)
        v += g1 * c3[(size_t)oc * 27 + (dz - 1) * 9 + (dy - 1) * 3 + (dx - 1)]
           + g3 * a3[oc] * (1.f / 27.f);
    if (dz == 2 && dy == 2 && dx == 2) v += g2 * c1[oc];
    int t = (dy * 5 + dx);
    int cich = ci >> 5, cil = ci & 31;
    wbuf[((((size_t)(n * 5 + dz) * (CI / 32) + cich) * 25 + t) * 64 + co) * 32 + cil] = f2bf(v);
}

// -------------------------------------------------------------- x->CL -----
__global__ __launch_bounds__(256) void x_to_cl(const float* __restrict__ x,
                                               unsigned short* __restrict__ xcl) {
    __shared__ float ld[32][256];
    int b = blockIdx.x;                   // 2048 = n(2) x 1024
    int n = b >> 10;
    size_t base = (size_t)(b & 1023) * 256;
    int tid = threadIdx.x;
    const float* xp = x + (size_t)n * 32 * SP + base + tid;
#pragma unroll
    for (int c = 0; c < 32; ++c) ld[c][tid] = xp[(size_t)c * SP];
    __syncthreads();
    uint4* op = (uint4*)(xcl + ((size_t)n * SP + base) * 32);
#pragma unroll
    for (int r = 0; r < 4; ++r) {
        int idx = r * 256 + tid;
        int px = idx >> 2, q = idx & 3;
        uint4 o;
        o.x = pack2(ld[q * 8 + 0][px], ld[q * 8 + 1][px]);
        o.y = pack2(ld[q * 8 + 2][px], ld[q * 8 + 3][px]);
        o.z = pack2(ld[q * 8 + 4][px], ld[q * 8 + 5][px]);
        o.w = pack2(ld[q * 8 + 6][px], ld[q * 8 + 7][px]);
        op[idx] = o;
    }
}

// ----------------------------------------------------------- MFMA conv ----
// Input bf16 channel-last [n][zyx][CI]. Block (512 thr): (n,z,yt,xt) ->
// 64co x 16y x 16x. Wave (yh,cq): 8 y-rows x 16 co. global_load_lds with
// PRE-SWIZZLED global source (linear LDS dest), XOR-swizzled ds_read.
// IN-stats partials: part[n][s][co][2048 chunks].
template <int CI, bool OUT_CL, int PCH>
__global__ __launch_bounds__(512, 4) void conv5_mfma(const unsigned short* __restrict__ xin,
                                                     const unsigned short* __restrict__ wbuf,
                                                     void* __restrict__ outp,
                                                     float* __restrict__ part,
                                                     const void* __restrict__ zbuf) {
    constexpr int NCH = CI / 32;
    constexpr int NS  = 5 * NCH;
    __shared__ __align__(16) unsigned short lds[2][12800];   // 2 x 25.6 KB

    const int b   = blockIdx.x;
    const int xt  = b & 3;
    const int yt  = (b >> 2) & 3;
    const int z   = (b >> 4) & 63;
    const int n   = b >> 10;
    const int tid = threadIdx.x;
    const int lane = tid & 63, wv = tid >> 6;
    const int xl = lane & 15, kh = lane >> 4;
    const int yh = wv >> 2, cq = wv & 3;

    f32x4 acc[8];
#pragma unroll
    for (int pt = 0; pt < 8; ++pt)
#pragma unroll
        for (int j = 0; j < 4; ++j) acc[pt][j] = 0.f;

    // staging geometry: LDS slot idx = tid + r*512 (linear dest, 16B each).
    // slot (p=idx>>2, khs=idx&3) holds global chunk khs^(xx&3) (involution).
    long goff[4]; int gval[4];
#pragma unroll
    for (int r = 0; r < 4; ++r) {
        int idx = tid + r * 512;
        int p = idx >> 2, khs = idx & 3;
        int xx = p % 20, yy = p / 20;
        int khs_g = khs ^ (xx & 3);
        int yi = yt * 16 - 2 + yy, xi = xt * 16 - 2 + xx;
        gval[r] = ((unsigned)yi < 64u) && ((unsigned)xi < 64u);
        goff[r] = ((long)(yi * 64 + xi) * CI + khs_g * 8) * 2;
    }

    auto stage = [&](int s, int buf) {
        int dz = s / NCH, cich = s % NCH;
        int zi = z + dz - 2;
        bool zok = (unsigned)zi < 64u;
        const char* pb = (const char*)xin
                       + ((size_t)(n * SP + zi * 4096) * CI + cich * 32) * 2;
        char* lb = (char*)&lds[buf][0];
#pragma unroll
        for (int r = 0; r < 4; ++r) {
            int idx = tid + r * 512;
            if (idx < 1600) {
                const void* g = (zok && gval[r]) ? (const void*)(pb + goff[r]) : zbuf;
                gload_lds16(g, lb + idx * 16);
            }
        }
    };

    auto compute = [&](int s, int buf) {
        int dz = s / NCH, cich = s % NCH;
        const unsigned short* wp = wbuf
            + ((size_t)((n * 5 + dz) * NCH + cich) * 25) * 2048
            + cq * 512 + xl * 32 + kh * 8;
        const char* src = (const char*)&lds[buf][0];
        __builtin_amdgcn_s_setprio(1);
#pragma unroll 1
        for (int dx = 0; dx < 5; ++dx) {
            int xx = xl + dx;
            unsigned int swz = (unsigned)(xx & 3) << 4;
            s16x8 fr[12];
#pragma unroll
            for (int r = 0; r < 12; ++r) {
                int row = yh * 8 + r;
                fr[r] = *(const s16x8*)(src
                        + (((unsigned)(row * 20 + xx) * 64 + (unsigned)kh * 16) ^ swz));
            }
#pragma unroll
            for (int dy = 0; dy < 5; ++dy) {
                s16x8 a = *(const s16x8*)(wp + (size_t)(dy * 5 + dx) * 2048);
#pragma unroll
                for (int pt = 0; pt < 8; ++pt)
                    acc[pt] = __builtin_amdgcn_mfma_f32_16x16x32_bf16(
                        a, fr[pt + dy], acc[pt], 0, 0, 0);
            }
        }
        __builtin_amdgcn_s_setprio(0);
    };

    stage(0, 0);
    __syncthreads();
#pragma unroll 1
    for (int s = 0; s < NS; ++s) {
        if (s + 1 < NS) stage(s + 1, (s + 1) & 1);
        compute(s, s & 1);
        __syncthreads();
    }

    // ---- fused instance-norm partial sums -> part[n][s][co][PCH] ----
    {
        float s1[4], s2[4];
#pragma unroll
        for (int j = 0; j < 4; ++j) { s1[j] = 0.f; s2[j] = 0.f; }
#pragma unroll
        for (int pt = 0; pt < 8; ++pt)
#pragma unroll
            for (int j = 0; j < 4; ++j) {
                float v = acc[pt][j];
                s1[j] += v; s2[j] += v * v;
            }
#pragma unroll
        for (int o = 1; o < 16; o <<= 1)
#pragma unroll
            for (int j = 0; j < 4; ++j) {
                s1[j] += __shfl_xor(s1[j], o, 64);
                s2[j] += __shfl_xor(s2[j], o, 64);
            }
        if (xl == 0) {
            int co = cq * 16 + kh * 4;
            int cb = (b & 1023) * 2 + yh;
#pragma unroll
            for (int j = 0; j < 4; ++j) {
                part[((size_t)(n * 2 + 0) * 64 + co + j) * PCH + cb] = s1[j];
                part[((size_t)(n * 2 + 1) * 64 + co + j) * PCH + cb] = s2[j];
            }
        }
    }

    if (OUT_CL) {
        // transpose via XOR-swizzled LDS [pix(256)][co(64)] bf16 -> coalesced
        char* tb = (char*)&lds[0][0];     // 32 KB
#pragma unroll
        for (int pt = 0; pt < 8; ++pt) {
            int pix = (yh * 8 + pt) * 16 + xl;
            unsigned int ad = ((unsigned)(pix * 128 + cq * 32 + kh * 8))
                              ^ ((unsigned)(pix & 7) << 4);
            *(unsigned int*)(tb + ad)     = pack2(acc[pt][0], acc[pt][1]);
            *(unsigned int*)(tb + ad + 4) = pack2(acc[pt][2], acc[pt][3]);
        }
        __syncthreads();
#pragma unroll
        for (int it = 0; it < 4; ++it) {
            int idx = it * 512 + tid;
            int pix = idx >> 3, ch = idx & 7;
            uint4 v = *(const uint4*)(tb + (((unsigned)idx * 16)
                                            ^ ((unsigned)(pix & 7) << 4)));
            int y = yt * 16 + (pix >> 4), x = xt * 16 + (pix & 15);
            *(uint4*)((unsigned short*)outp
                      + ((size_t)(n * SP + z * 4096 + y * 64 + x) * 64 + ch * 8)) = v;
        }
    } else {
        float* op = (float*)outp;
#pragma unroll
        for (int pt = 0; pt < 8; ++pt) {
            int y = yt * 16 + yh * 8 + pt;
#pragma unroll
            for (int j = 0; j < 4; ++j)
                op[((size_t)(n * 64 + cq * 16 + kh * 4 + j) * 64 + z) * 4096
                   + y * 64 + xt * 16 + xl] = acc[pt][j];
        }
    }
}

// ------------------------------------------------- stats finalize ---------
// part: [n][s][co][CH] contiguous rows. grid = 128 (n*64+co), 256 thr.
template <int CH>
__global__ void stats_fin(const float* __restrict__ part, float* __restrict__ st,
                          float invS) {
    int blk = blockIdx.x;
    int n = blk >> 6, co = blk & 63;
    int tid = threadIdx.x;
    const float* ps = part + ((size_t)(n * 2 + 0) * 64 + co) * CH;
    const float* pq = part + ((size_t)(n * 2 + 1) * 64 + co) * CH;
    float s1 = 0.f, s2 = 0.f;
    for (int i = tid; i < CH; i += 256) { s1 += ps[i]; s2 += pq[i]; }
#pragma unroll
    for (int o = 1; o < 64; o <<= 1) {
        s1 += __shfl_xor(s1, o, 64);
        s2 += __shfl_xor(s2, o, 64);
    }
    __shared__ float sh1[4], sh2[4];
    if ((tid & 63) == 0) { sh1[tid >> 6] = s1; sh2[tid >> 6] = s2; }
    __syncthreads();
    if (tid == 0) {
        float a = sh1[0] + sh1[1] + sh1[2] + sh1[3];
        float q = sh2[0] + sh2[1] + sh2[2] + sh2[3];
        float mean = a * invS;
        float var  = q * invS - mean * mean;
        st[(n * 64 + co) * 2]     = mean;
        st[(n * 64 + co) * 2 + 1] = rsqrtf(var + 1e-5f);
    }
}

// -------------------------------------- norm+mish in-place, channel-last --
__global__ void norm_mish_cl_kernel(unsigned short* __restrict__ h,
                                    const float* __restrict__ st,
                                    const float* __restrict__ gamma,
                                    const float* __restrict__ beta) {
    size_t idx = (size_t)blockIdx.x * 256 + threadIdx.x;   // NB*SP*8 items
    uint4 v = ((uint4*)h)[idx];
    int c0 = ((int)(idx & 7)) * 8;
    size_t pix = idx >> 3;
    int n = (int)(pix >> 18);
    unsigned int* pv = &v.x;
#pragma unroll
    for (int q = 0; q < 4; ++q) {
        unsigned int wv = pv[q];
        unsigned int out = 0;
#pragma unroll
        for (int hv = 0; hv < 2; ++hv) {
            int c = c0 + 2 * q + hv;
            int nc = n * 64 + c;
            float val = bf2f((unsigned short)((wv >> (16 * hv)) & 0xffffu));
            float xh = (val - st[nc * 2]) * st[nc * 2 + 1] * gamma[c] + beta[c];
            out |= ((unsigned int)f2bf(mish_f(xh))) << (16 * hv);
        }
        pv[q] = out;
    }
    ((uint4*)h)[idx] = v;
}

// ----------------------------------------------------------- norm+mish ----
template <int SHIFT>
__global__ void norm_mish_kernel(float* __restrict__ buf, const float* __restrict__ stats,
                                 const float* __restrict__ gamma, const float* __restrict__ beta,
                                 int total4) {
    int idx = blockIdx.x * 256 + threadIdx.x;
    if (idx >= total4) return;
    float4 v = reinterpret_cast<float4*>(buf)[idx];
    int nc = idx >> (SHIFT - 2);
    int c  = nc & 63;
    float mean = stats[nc * 2], inv = stats[nc * 2 + 1];
    float ga = gamma[c], be = beta[c];
    float* pv = &v.x;
#pragma unroll
    for (int k = 0; k < 4; ++k) {
        float xh = (pv[k] - mean) * inv * ga + be;
        pv[k] = mish_f(xh);
    }
    reinterpret_cast<float4*>(buf)[idx] = v;
}

// ----------------------------------------------------------- down conv ----
// Fused: reads RAW xskip, applies norm+mish (st2), writes normalized back,
// 2x2x2 stride-2 conv, writes raw y + y-stats partials [n][s][co][256].
__global__ __launch_bounds__(256) void down_conv_kernel(float* __restrict__ xin,
                                                        const float* __restrict__ dw,
                                                        const float* __restrict__ st,
                                                        const float* __restrict__ gamma,
                                                        const float* __restrict__ beta,
                                                        float* __restrict__ out,
                                                        float* __restrict__ part) {
    __shared__ float ls[8][2][8][64];
    int b   = blockIdx.x;
    int yt  = b & 7;
    int z   = (b >> 3) & 31;
    int n   = b >> 8;
    int tid = threadIdx.x;
    int xo  = tid & 31;
    int cog = tid >> 5;

    float acc[4][8];
#pragma unroll
    for (int yo = 0; yo < 4; ++yo)
#pragma unroll
        for (int j = 0; j < 8; ++j) acc[yo][j] = 0.f;

    for (int cc = 0; cc < 8; ++cc) {
        for (int idx = tid; idx < 8192; idx += 256) {
            int xx = idx & 63;
            int yy = (idx >> 6) & 7;
            int dz = (idx >> 9) & 1;
            int c  = idx >> 10;
            int ci = cc * 8 + c;
            size_t ga = ((size_t)(n * CO + ci) * 64 + 2 * z + dz) * 4096
                      + (yt * 8 + yy) * 64 + xx;
            float v = xin[ga];
            int nc = n * 64 + ci;
            float nv = mish_f((v - st[nc * 2]) * st[nc * 2 + 1] * gamma[ci] + beta[ci]);
            ls[c][dz][yy][xx] = nv;
            xin[ga] = nv;
        }
        __syncthreads();
#pragma unroll 1
        for (int c = 0; c < 8; ++c) {
            int ci = cc * 8 + c;
#pragma unroll
            for (int tap = 0; tap < 8; ++tap) {
                int dz = tap >> 2, dy = (tap >> 1) & 1, dx = tap & 1;
                float w[8];
#pragma unroll
                for (int j = 0; j < 8; ++j)
                    w[j] = dw[((size_t)(cog * 8 + j) * CO + ci) * 8 + tap];
#pragma unroll
                for (int yo = 0; yo < 4; ++yo) {
                    float xv = ls[c][dz][yo * 2 + dy][2 * xo + dx];
#pragma unroll
                    for (int j = 0; j < 8; ++j) acc[yo][j] += w[j] * xv;
                }
            }
        }
        __syncthreads();
    }
#pragma unroll
    for (int yo = 0; yo < 4; ++yo)
#pragma unroll
        for (int j = 0; j < 8; ++j)
            out[((size_t)(n * CO + cog * 8 + j) * 32 + z) * 1024 + (yt * 4 + yo) * 32 + xo]
                = acc[yo][j];

    // y-stats partials
    float s1[8], s2[8];
#pragma unroll
    for (int j = 0; j < 8; ++j) { s1[j] = 0.f; s2[j] = 0.f; }
#pragma unroll
    for (int yo = 0; yo < 4; ++yo)
#pragma unroll
        for (int j = 0; j < 8; ++j) {
            float v = acc[yo][j];
            s1[j] += v; s2[j] += v * v;
        }
#pragma unroll
    for (int o = 1; o < 32; o <<= 1)
#pragma unroll
        for (int j = 0; j < 8; ++j) {
            s1[j] += __shfl_xor(s1[j], o, 64);
            s2[j] += __shfl_xor(s2[j], o, 64);
        }
    if (xo == 0) {
        int cb = b & 255;
#pragma unroll
        for (int j = 0; j < 8; ++j) {
            int co = cog * 8 + j;
            part[((size_t)(n * 2 + 0) * 64 + co) * 256 + cb] = s1[j];
            part[((size_t)(n * 2 + 1) * 64 + co) * 256 + cb] = s2[j];
        }
    }
}

// -------------------------------------------------------------- launch ----
extern "C" void kernel_launch(void* const* d_in, const int* in_sizes, int n_in,
                              void* d_out, int out_size, void* d_ws, size_t ws_size,
                              hipStream_t stream) {
    const float* x      = (const float*)d_in[0];
    const float* t      = (const float*)d_in[1];
    const float* l1_c5  = (const float*)d_in[2];
    const float* l1_c3  = (const float*)d_in[3];
    const float* l1_c1  = (const float*)d_in[4];
    const float* l1_a3  = (const float*)d_in[5];
    const float* l1_a5  = (const float*)d_in[6];
    const float* l1_gw  = (const float*)d_in[7];
    const float* l1_gb  = (const float*)d_in[8];
    const float* l1_ga  = (const float*)d_in[9];
    const float* l1_be  = (const float*)d_in[10];
    const float* l2_c5  = (const float*)d_in[11];
    const float* l2_c3  = (const float*)d_in[12];
    const float* l2_c1  = (const float*)d_in[13];
    const float* l2_a3  = (const float*)d_in[14];
    const float* l2_a5  = (const float*)d_in[15];
    const float* l2_gw  = (const float*)d_in[16];
    const float* l2_gb  = (const float*)d_in[17];
    const float* l2_ga  = (const float*)d_in[18];
    const float* l2_be  = (const float*)d_in[19];
    const float* down_w = (const float*)d_in[20];
    const float* dn_ga  = (const float*)d_in[21];
    const float* dn_be  = (const float*)d_in[22];

    char* ws = (char*)d_ws;
    unsigned short* xcl = (unsigned short*)(ws);                  // 33,554,432 B
    unsigned short* h2  = (unsigned short*)(ws + 33554432);       // 67,108,864 B
    unsigned short* w1  = (unsigned short*)(ws + 100663296);      //  1,024,000 B
    unsigned short* w2  = (unsigned short*)(ws + 101687296);      //  2,048,000 B
    float* g1    = (float*)(ws + 103735296);
    float* g2    = (float*)(ws + 103737856);
    float* st1   = (float*)(ws + 103740416);
    float* st2   = (float*)(ws + 103741440);
    float* st3   = (float*)(ws + 103742464);
    float* part1 = (float*)(ws + 103743488);                      //  2,097,152 B
    float* part2 = (float*)(ws + 105840640);                      //  2,097,152 B
    float* part3 = (float*)(ws + 107937792);                      //    262,144 B
    float* zbuf  = (float*)(ws + 108199936);                      //        256 B

    float* yout  = (float*)d_out;
    float* xskip = (float*)d_out + Y_SZ;

    gate_kernel<<<1, 192, 0, stream>>>(t, l1_gw, l1_gb, g1, zbuf);
    gate_kernel<<<1, 192, 0, stream>>>(t, l2_gw, l2_gb, g2, zbuf);
    synth_kernel<32><<<(NB * CO * 32 * 125 + 255) / 256, 256, 0, stream>>>(
        g1, l1_c5, l1_c3, l1_c1, l1_a3, l1_a5, w1);
    synth_kernel<64><<<(NB * CO * 64 * 125 + 255) / 256, 256, 0, stream>>>(
        g2, l2_c5, l2_c3, l2_c1, l2_a3, l2_a5, w2);
    x_to_cl<<<2048, 256, 0, stream>>>(x, xcl);

    // layer 1: conv (bf16 CL in -> bf16 CL raw out) + fused stats partials
    conv5_mfma<32, true, 2048><<<2048, 512, 0, stream>>>(xcl, w1, h2, part1, zbuf);
    stats_fin<2048><<<128, 256, 0, stream>>>(part1, st1, 1.f / SP);
    norm_mish_cl_kernel<<<16384, 256, 0, stream>>>(h2, st1, l1_ga, l1_be);

    // layer 2: conv (bf16 CL in -> f32 NCDHW raw into x_skip) + partials
    conv5_mfma<64, false, 2048><<<2048, 512, 0, stream>>>(h2, w2, xskip, part2, zbuf);
    stats_fin<2048><<<128, 256, 0, stream>>>(part2, st2, 1.f / SP);

    // downsample: fused norm+mish(x_skip, in place) + conv + y-stats partials
    down_conv_kernel<<<NB * 32 * 8, 256, 0, stream>>>(xskip, down_w, st2, l2_ga, l2_be,
                                                      yout, part3);
    stats_fin<256><<<128, 256, 0, stream>>>(part3, st3, 1.f / 32768.f);
    norm_mish_kernel<15><<<(NC * 32768 / 4 + 255) / 256, 256, 0, stream>>>(
        yout, st3, dn_ga, dn_be, NC * 32768 / 4);
}